// Round 6
// baseline (639.975 us; speedup 1.0000x reference)
//
#include <hip/hip_runtime.h>
#include <hip/hip_bf16.h>

#define HDIM 128
#define FIN  32

typedef __hip_bfloat16 bf16t;
using bf16x8 = __attribute__((ext_vector_type(8))) short;
using f32x4  = __attribute__((ext_vector_type(4))) float;

__device__ __forceinline__ float reluf(float x) { return x > 0.f ? x : 0.f; }

__device__ __forceinline__ unsigned short f2bf(float f) {
    unsigned int b = __float_as_uint(f);
    b += 0x7FFFu + ((b >> 16) & 1u);       // round-to-nearest-even
    return (unsigned short)(b >> 16);
}
__device__ __forceinline__ float bf2f(unsigned short u) {
    return __uint_as_float(((unsigned int)u) << 16);
}

__device__ __forceinline__ float4 ld4(const bf16t* p) {
    ushort4 u = *(const ushort4*)p;
    return make_float4(bf2f(u.x), bf2f(u.y), bf2f(u.z), bf2f(u.w));
}
__device__ __forceinline__ void st4(bf16t* p, float4 v) {
    ushort4 u;
    u.x = f2bf(v.x); u.y = f2bf(v.y); u.z = f2bf(v.z); u.w = f2bf(v.w);
    *(ushort4*)p = u;
}

// ======================= CSR construction ===================================
__global__ __launch_bounds__(256) void hist_kernel(
    const int* __restrict__ dst, int* __restrict__ deg, int E)
{
    int i = blockIdx.x * 256 + threadIdx.x;
    if (i < E) atomicAdd(&deg[dst[i]], 1);
}

__global__ __launch_bounds__(256) void scan_blocks_kernel(
    const int* __restrict__ deg, int* __restrict__ start,
    int* __restrict__ bsum, int N)
{
    __shared__ int s[256];
    const int t = threadIdx.x;
    const int base = blockIdx.x * 1024;
    int v[4], tsum = 0;
    #pragma unroll
    for (int i = 0; i < 4; ++i) {
        int idx = base + t * 4 + i;
        v[i] = (idx < N) ? deg[idx] : 0;
        tsum += v[i];
    }
    s[t] = tsum; __syncthreads();
    for (int off = 1; off < 256; off <<= 1) {
        int x = (t >= off) ? s[t - off] : 0;
        __syncthreads();
        s[t] += x;
        __syncthreads();
    }
    if (t == 255) bsum[blockIdx.x] = s[255];
    int run = s[t] - tsum;
    #pragma unroll
    for (int i = 0; i < 4; ++i) {
        int idx = base + t * 4 + i;
        if (idx < N) start[idx] = run;
        run += v[i];
    }
}

__global__ __launch_bounds__(256) void scan_top_kernel(int* __restrict__ bsum, int B)
{
    __shared__ int s[256];
    const int t = threadIdx.x;
    int v[4], tsum = 0;
    #pragma unroll
    for (int i = 0; i < 4; ++i) {
        int idx = t * 4 + i;
        v[i] = (idx < B) ? bsum[idx] : 0;
        tsum += v[i];
    }
    s[t] = tsum; __syncthreads();
    for (int off = 1; off < 256; off <<= 1) {
        int x = (t >= off) ? s[t - off] : 0;
        __syncthreads();
        s[t] += x;
        __syncthreads();
    }
    int run = s[t] - tsum;
    #pragma unroll
    for (int i = 0; i < 4; ++i) {
        int idx = t * 4 + i;
        if (idx < B) bsum[idx] = run;
        run += v[i];
    }
}

__global__ __launch_bounds__(256) void scan_add_kernel(
    int* __restrict__ start, int* __restrict__ cursor,
    const int* __restrict__ bsum, int N)
{
    int i = blockIdx.x * 256 + threadIdx.x;
    if (i < N) {
        int v = start[i] + bsum[i >> 10];
        start[i]  = v;
        cursor[i] = v;
    }
}

__global__ __launch_bounds__(256) void fill_kernel(
    const int* __restrict__ src, const int* __restrict__ dst,
    int* __restrict__ cursor, int* __restrict__ eidx, int E)
{
    int i = blockIdx.x * 256 + threadIdx.x;
    if (i < E) {
        int d = dst[i];
        int p = atomicAdd(&cursor[d], 1);
        eidx[p] = src[i];
    }
}

// ======================= weight repack (MFMA A-fragment order) ==============
// A-frag: lane l, elem j holds A[m = mt*16 + (l&15)][k = kc*32 + (l>>4)*8 + j]
// with A = W^T, i.e. value W[k][m], stored at P[((kc*NMT + mt)*64 + l)*8 + j].
__global__ __launch_bounds__(256) void pack_w1_kernel(
    const float* __restrict__ W1t, bf16t* __restrict__ W1P, int total)
{
    int q = blockIdx.x * 256 + threadIdx.x;
    if (q >= total) return;
    int L = q >> 15;                 // 32768 per level (K=256, 8 kc x 8 mt)
    int r = q & 32767;
    int j = r & 7, l = (r >> 3) & 63, mt = (r >> 9) & 7, kc = (r >> 12) & 7;
    float v = W1t[(size_t)L * 2 * HDIM * HDIM +
                  (size_t)(kc * 32 + ((l >> 4) & 3) * 8 + j) * HDIM + mt * 16 + (l & 15)];
    *(unsigned short*)&W1P[q] = f2bf(v);
}

__global__ __launch_bounds__(256) void pack_w2_kernel(
    const float* __restrict__ W2t, bf16t* __restrict__ W2P, int total)
{
    int q = blockIdx.x * 256 + threadIdx.x;
    if (q >= total) return;
    int L = q >> 14;                 // 16384 per level (K=128, 4 kc x 8 mt)
    int r = q & 16383;
    int j = r & 7, l = (r >> 3) & 63, mt = (r >> 9) & 7, kc = (r >> 12) & 3;
    float v = W2t[(size_t)L * HDIM * HDIM +
                  (size_t)(kc * 32 + ((l >> 4) & 3) * 8 + j) * HDIM + mt * 16 + (l & 15)];
    *(unsigned short*)&W2P[q] = f2bf(v);
}

// K=32 encoder weights: 6 encoders x (8 mt x 64 l x 8 j) = 6*4096
__global__ __launch_bounds__(256) void pack_we_kernel(
    const float* __restrict__ We, bf16t* __restrict__ WeP, int total)
{
    int q = blockIdx.x * 256 + threadIdx.x;
    if (q >= total) return;
    int enc = q >> 12;
    int r = q & 4095;
    int j = r & 7, l = (r >> 3) & 63, mt = (r >> 9) & 7;
    int k = ((l >> 4) & 3) * 8 + j;
    float v = We[(size_t)enc * FIN * HDIM + (size_t)k * HDIM + mt * 16 + (l & 15)];
    *(unsigned short*)&WeP[q] = f2bf(v);
}

// ======================= MFMA encoder (h_col only) ==========================
__global__ __launch_bounds__(256) void enc_mfma_kernel(
    const float* __restrict__ x, const bf16t* __restrict__ WP,
    const float* __restrict__ b, bf16t* __restrict__ h, int N)
{
    __shared__ bf16t x_s[64 * 36];
    const int tid  = threadIdx.x;
    const int row0 = blockIdx.x * 64;
    const int wave = tid >> 6, lane = tid & 63;
    const int l15 = lane & 15, l16 = lane >> 4;

    #pragma unroll
    for (int i = 0; i < 2; ++i) {
        int f = tid + i * 256;
        int r = f >> 3, c4 = f & 7;
        int row = row0 + r; if (row >= N) row = N - 1;
        float4 v = *(const float4*)&x[(size_t)row * FIN + c4 * 4];
        ushort4 u;
        u.x = f2bf(v.x); u.y = f2bf(v.y); u.z = f2bf(v.z); u.w = f2bf(v.w);
        *(ushort4*)&x_s[r * 36 + c4 * 4] = u;
    }
    __syncthreads();

    f32x4 acc[2][4];
    #pragma unroll
    for (int m = 0; m < 2; ++m)
        #pragma unroll
        for (int n = 0; n < 4; ++n)
            #pragma unroll
            for (int i = 0; i < 4; ++i) acc[m][n][i] = 0.f;

    bf16x8 a[2], bb[4];
    #pragma unroll
    for (int m = 0; m < 2; ++m)
        a[m] = *(const bf16x8*)&WP[(((wave * 2 + m)) * 64 + lane) * 8];
    #pragma unroll
    for (int n = 0; n < 4; ++n)
        bb[n] = *(const bf16x8*)&x_s[(n * 16 + l15) * 36 + l16 * 8];
    #pragma unroll
    for (int m = 0; m < 2; ++m)
        #pragma unroll
        for (int n = 0; n < 4; ++n)
            acc[m][n] = __builtin_amdgcn_mfma_f32_16x16x32_bf16(a[m], bb[n], acc[m][n], 0, 0, 0);

    #pragma unroll
    for (int m = 0; m < 2; ++m) {
        int mt = wave * 2 + m;
        float4 bv = *(const float4*)&b[mt * 16 + l16 * 4];
        #pragma unroll
        for (int n = 0; n < 4; ++n) {
            int row = row0 + n * 16 + l15;
            if (row < N) {
                ushort4 u;
                u.x = f2bf(reluf(acc[m][n][0] + bv.x));
                u.y = f2bf(reluf(acc[m][n][1] + bv.y));
                u.z = f2bf(reluf(acc[m][n][2] + bv.z));
                u.w = f2bf(reluf(acc[m][n][3] + bv.w));
                *(ushort4*)&h[(size_t)row * HDIM + mt * 16 + l16 * 4] = u;
            }
        }
    }
}

// ======================= fused level kernel =================================
// Per 64-row dst tile:
//  (1) stage x_dst (bf16) -> z_s (stride 36)
//  (2) inline encoder MFMA -> act_s[:,0:128]
//  (3) inline CSR gather (sum h_src[eidx]) -> act_s[:,128:256]
//  (4) GEMM1 (K=256) -> z1 -> z_s (stride 136)
//  (5) GEMM2 (K=128) -> h_out
#define ACT_STRIDE 264   // 256 + 8 bf16 pad
#define Z_STRIDE   136   // 128 + 8 bf16 pad
__global__ __launch_bounds__(256) void fused_combine_kernel(
    const float* __restrict__ x, const bf16t* __restrict__ WEPl,
    const float* __restrict__ be,
    const bf16t* __restrict__ hsrc, const int* __restrict__ eidx,
    const int* __restrict__ start, const int* __restrict__ deg,
    const bf16t* __restrict__ W1P, const float* __restrict__ b1,
    const bf16t* __restrict__ W2P, const float* __restrict__ b2,
    bf16t* __restrict__ hout, int N)
{
    __shared__ bf16t act_s[64 * ACT_STRIDE];   // 33,792 B
    __shared__ bf16t z_s[64 * Z_STRIDE];       // 17,408 B (x-tile first, then z1)

    const int tid  = threadIdx.x;
    const int row0 = blockIdx.x * 64;
    const int wave = tid >> 6, lane = tid & 63;
    const int l15 = lane & 15, l16 = lane >> 4;

    // (1) stage x tile as bf16, stride 36
    #pragma unroll
    for (int i = 0; i < 2; ++i) {
        int f = tid + i * 256;               // float4 idx in 64x32
        int r = f >> 3, c4 = f & 7;
        int row = row0 + r; if (row >= N) row = N - 1;
        float4 v = *(const float4*)&x[(size_t)row * FIN + c4 * 4];
        ushort4 u;
        u.x = f2bf(v.x); u.y = f2bf(v.y); u.z = f2bf(v.z); u.w = f2bf(v.w);
        *(ushort4*)&z_s[r * 36 + c4 * 4] = u;
    }
    __syncthreads();

    // (2) inline encoder: h_dst tile -> act_s[:,0:128]
    {
        f32x4 eacc[2][4];
        #pragma unroll
        for (int m = 0; m < 2; ++m)
            #pragma unroll
            for (int n = 0; n < 4; ++n)
                #pragma unroll
                for (int i = 0; i < 4; ++i) eacc[m][n][i] = 0.f;

        bf16x8 a[2], bb[4];
        #pragma unroll
        for (int m = 0; m < 2; ++m)
            a[m] = *(const bf16x8*)&WEPl[(((wave * 2 + m)) * 64 + lane) * 8];
        #pragma unroll
        for (int n = 0; n < 4; ++n)
            bb[n] = *(const bf16x8*)&z_s[(n * 16 + l15) * 36 + l16 * 8];
        #pragma unroll
        for (int m = 0; m < 2; ++m)
            #pragma unroll
            for (int n = 0; n < 4; ++n)
                eacc[m][n] = __builtin_amdgcn_mfma_f32_16x16x32_bf16(a[m], bb[n], eacc[m][n], 0, 0, 0);

        #pragma unroll
        for (int m = 0; m < 2; ++m) {
            int mt = wave * 2 + m;
            float4 bv = *(const float4*)&be[mt * 16 + l16 * 4];
            #pragma unroll
            for (int n = 0; n < 4; ++n) {
                int rl = n * 16 + l15;
                ushort4 u;
                u.x = f2bf(reluf(eacc[m][n][0] + bv.x));
                u.y = f2bf(reluf(eacc[m][n][1] + bv.y));
                u.z = f2bf(reluf(eacc[m][n][2] + bv.z));
                u.w = f2bf(reluf(eacc[m][n][3] + bv.w));
                *(ushort4*)&act_s[rl * ACT_STRIDE + mt * 16 + l16 * 4] = u;
            }
        }
    }

    // (3) inline gather: msg tile -> act_s[:,128:256]  (32 lanes per row)
    {
        const int g = tid >> 5, l32 = tid & 31;
        #pragma unroll
        for (int it = 0; it < 8; ++it) {
            int rl = it * 8 + g;
            int row = row0 + rl;
            float4 acc = make_float4(0.f, 0.f, 0.f, 0.f);
            if (row < N) {
                int s0 = start[row], cnt = deg[row];
                for (int j = s0; j < s0 + cnt; ++j) {
                    int s = eidx[j];
                    float4 v = ld4(&hsrc[(size_t)s * HDIM + l32 * 4]);
                    acc.x += v.x; acc.y += v.y; acc.z += v.z; acc.w += v.w;
                }
            }
            st4(&act_s[rl * ACT_STRIDE + 128 + l32 * 4], acc);
        }
    }
    __syncthreads();

    // (4) GEMM1: K=256
    f32x4 acc1[2][4];
    #pragma unroll
    for (int m = 0; m < 2; ++m)
        #pragma unroll
        for (int n = 0; n < 4; ++n)
            #pragma unroll
            for (int i = 0; i < 4; ++i) acc1[m][n][i] = 0.f;

    for (int kc = 0; kc < 8; ++kc) {
        bf16x8 a[2], b[4];
        #pragma unroll
        for (int m = 0; m < 2; ++m) {
            int mt = wave * 2 + m;
            a[m] = *(const bf16x8*)&W1P[((kc * 8 + mt) * 64 + lane) * 8];
        }
        #pragma unroll
        for (int n = 0; n < 4; ++n)
            b[n] = *(const bf16x8*)&act_s[(n * 16 + l15) * ACT_STRIDE + kc * 32 + l16 * 8];
        #pragma unroll
        for (int m = 0; m < 2; ++m)
            #pragma unroll
            for (int n = 0; n < 4; ++n)
                acc1[m][n] = __builtin_amdgcn_mfma_f32_16x16x32_bf16(a[m], b[n], acc1[m][n], 0, 0, 0);
    }

    // z1 = relu(acc1+b1) -> z_s (stride 136); x-tile is dead (all waves past barrier)
    #pragma unroll
    for (int m = 0; m < 2; ++m) {
        int mt = wave * 2 + m;
        float4 bb = *(const float4*)&b1[mt * 16 + l16 * 4];
        #pragma unroll
        for (int n = 0; n < 4; ++n) {
            int zrow = n * 16 + l15;
            ushort4 u;
            u.x = f2bf(reluf(acc1[m][n][0] + bb.x));
            u.y = f2bf(reluf(acc1[m][n][1] + bb.y));
            u.z = f2bf(reluf(acc1[m][n][2] + bb.z));
            u.w = f2bf(reluf(acc1[m][n][3] + bb.w));
            *(ushort4*)&z_s[zrow * Z_STRIDE + mt * 16 + l16 * 4] = u;
        }
    }
    __syncthreads();

    // (5) GEMM2: K=128
    f32x4 acc2[2][4];
    #pragma unroll
    for (int m = 0; m < 2; ++m)
        #pragma unroll
        for (int n = 0; n < 4; ++n)
            #pragma unroll
            for (int i = 0; i < 4; ++i) acc2[m][n][i] = 0.f;

    for (int kc = 0; kc < 4; ++kc) {
        bf16x8 a[2], b[4];
        #pragma unroll
        for (int m = 0; m < 2; ++m) {
            int mt = wave * 2 + m;
            a[m] = *(const bf16x8*)&W2P[((kc * 8 + mt) * 64 + lane) * 8];
        }
        #pragma unroll
        for (int n = 0; n < 4; ++n)
            b[n] = *(const bf16x8*)&z_s[(n * 16 + l15) * Z_STRIDE + kc * 32 + l16 * 8];
        #pragma unroll
        for (int m = 0; m < 2; ++m)
            #pragma unroll
            for (int n = 0; n < 4; ++n)
                acc2[m][n] = __builtin_amdgcn_mfma_f32_16x16x32_bf16(a[m], b[n], acc2[m][n], 0, 0, 0);
    }

    #pragma unroll
    for (int m = 0; m < 2; ++m) {
        int mt = wave * 2 + m;
        float4 bb = *(const float4*)&b2[mt * 16 + l16 * 4];
        #pragma unroll
        for (int n = 0; n < 4; ++n) {
            int row = row0 + n * 16 + l15;
            if (row < N) {
                ushort4 u;
                u.x = f2bf(reluf(acc2[m][n][0] + bb.x));
                u.y = f2bf(reluf(acc2[m][n][1] + bb.y));
                u.z = f2bf(reluf(acc2[m][n][2] + bb.z));
                u.w = f2bf(reluf(acc2[m][n][3] + bb.w));
                *(ushort4*)&hout[(size_t)row * HDIM + mt * 16 + l16 * 4] = u;
            }
        }
    }
}

// ======================= fused final MLP + rowdot ===========================
__global__ __launch_bounds__(256) void finale_kernel(
    const bf16t* __restrict__ he, const bf16t* __restrict__ W1P,
    const float* __restrict__ b1, const float* __restrict__ w2,
    const float* __restrict__ b2, float* __restrict__ out, int N)
{
    __shared__ bf16t a_s[64 * Z_STRIDE];
    __shared__ float o_s[64];

    const int tid  = threadIdx.x;
    const int row0 = blockIdx.x * 64;
    const int wave = tid >> 6, lane = tid & 63;
    const int l15 = lane & 15, l16 = lane >> 4;

    if (tid < 64) o_s[tid] = 0.f;
    #pragma unroll
    for (int i = 0; i < 4; ++i) {
        int f = tid + i * 256;
        int r = f >> 4, seg = f & 15;
        int row = row0 + r; if (row >= N) row = N - 1;
        *(float4*)&a_s[r * Z_STRIDE + seg * 8] =
            *(const float4*)&he[(size_t)row * HDIM + seg * 8];
    }
    __syncthreads();

    f32x4 acc[2][4];
    #pragma unroll
    for (int m = 0; m < 2; ++m)
        #pragma unroll
        for (int n = 0; n < 4; ++n)
            #pragma unroll
            for (int i = 0; i < 4; ++i) acc[m][n][i] = 0.f;

    for (int kc = 0; kc < 4; ++kc) {
        bf16x8 a[2], b[4];
        #pragma unroll
        for (int m = 0; m < 2; ++m) {
            int mt = wave * 2 + m;
            a[m] = *(const bf16x8*)&W1P[((kc * 8 + mt) * 64 + lane) * 8];
        }
        #pragma unroll
        for (int n = 0; n < 4; ++n)
            b[n] = *(const bf16x8*)&a_s[(n * 16 + l15) * Z_STRIDE + kc * 32 + l16 * 8];
        #pragma unroll
        for (int m = 0; m < 2; ++m)
            #pragma unroll
            for (int n = 0; n < 4; ++n)
                acc[m][n] = __builtin_amdgcn_mfma_f32_16x16x32_bf16(a[m], b[n], acc[m][n], 0, 0, 0);
    }

    float s[4] = {0.f, 0.f, 0.f, 0.f};
    #pragma unroll
    for (int m = 0; m < 2; ++m) {
        int mt = wave * 2 + m;
        float4 bb = *(const float4*)&b1[mt * 16 + l16 * 4];
        float4 ww = *(const float4*)&w2[mt * 16 + l16 * 4];
        #pragma unroll
        for (int n = 0; n < 4; ++n) {
            s[n] += reluf(acc[m][n][0] + bb.x) * ww.x
                  + reluf(acc[m][n][1] + bb.y) * ww.y
                  + reluf(acc[m][n][2] + bb.z) * ww.z
                  + reluf(acc[m][n][3] + bb.w) * ww.w;
        }
    }
    #pragma unroll
    for (int n = 0; n < 4; ++n) {
        s[n] += __shfl_xor(s[n], 16, 64);
        s[n] += __shfl_xor(s[n], 32, 64);
        if (l16 == 0) atomicAdd(&o_s[n * 16 + l15], s[n]);
    }
    __syncthreads();
    if (tid < 64) {
        int row = row0 + tid;
        if (row < N) out[row] = o_s[tid] + b2[0];
    }
}

__global__ __launch_bounds__(256) void sentinel_kernel(float* out, int n, float val)
{
    int i = blockIdx.x * 256 + threadIdx.x;
    if (i < n) out[i] = (i == 0) ? val : 0.f;
}

// ---------------------------------------------------------------------------
static void build_csr(const int* src, const int* dst, int E, int N,
                      int* deg, int* start, int* cursor, int* eidx, int* bsum,
                      hipStream_t stream)
{
    const dim3 blk(256);
    hipMemsetAsync(deg, 0, (size_t)N * sizeof(int), stream);
    hist_kernel<<<dim3((E + 255) / 256), blk, 0, stream>>>(dst, deg, E);
    int B = (N + 1023) / 1024;
    scan_blocks_kernel<<<dim3(B), blk, 0, stream>>>(deg, start, bsum, N);
    scan_top_kernel<<<dim3(1), blk, 0, stream>>>(bsum, B);
    scan_add_kernel<<<dim3((N + 255) / 256), blk, 0, stream>>>(start, cursor, bsum, N);
    fill_kernel<<<dim3((E + 255) / 256), blk, 0, stream>>>(src, dst, cursor, eidx, E);
}

extern "C" void kernel_launch(void* const* d_in, const int* in_sizes, int n_in,
                              void* d_out, int out_size, void* d_ws, size_t ws_size,
                              hipStream_t stream)
{
    const float* x_col  = (const float*)d_in[0];
    const float* x_filt = (const float*)d_in[1];
    const float* x_pred = (const float*)d_in[2];
    const float* x_scan = (const float*)d_in[3];
    const float* x_join = (const float*)d_in[4];
    const float* x_enc  = (const float*)d_in[5];
    const float* W_enc  = (const float*)d_in[6];
    const float* b_enc  = (const float*)d_in[7];
    const float* W1t    = (const float*)d_in[8];
    const float* b1t    = (const float*)d_in[9];
    const float* W2t    = (const float*)d_in[10];
    const float* b2t    = (const float*)d_in[11];
    const float* Wf1    = (const float*)d_in[12];
    const float* bf1    = (const float*)d_in[13];
    const float* Wf2    = (const float*)d_in[14];
    const float* bf2    = (const float*)d_in[15];
    const int* src_cf = (const int*)d_in[16];
    const int* dst_cf = (const int*)d_in[17];
    const int* src_fp = (const int*)d_in[18];
    const int* dst_fp = (const int*)d_in[19];
    const int* src_ps = (const int*)d_in[20];
    const int* dst_ps = (const int*)d_in[21];
    const int* src_sj = (const int*)d_in[22];
    const int* dst_sj = (const int*)d_in[23];
    const int* src_je = (const int*)d_in[24];
    const int* dst_je = (const int*)d_in[25];

    const int N_COL  = in_sizes[0] / FIN;
    const int N_FILT = in_sizes[1] / FIN;
    const int N_PRED = in_sizes[2] / FIN;
    const int N_SCAN = in_sizes[3] / FIN;
    const int N_JOIN = in_sizes[4] / FIN;
    const int N_ENC  = in_sizes[5] / FIN;
    const int E_CF = in_sizes[16];
    const int E_FP = in_sizes[18];
    const int E_PS = in_sizes[20];
    const int E_SJ = in_sizes[22];
    const int E_JE = in_sizes[24];

    // ---- workspace layout ----
    // A region: h_col (N_COL rows); later re-used for h_pred/h_scan/h_join/h_enc
    // B region: h_filt (N_FILT rows)
    size_t sumP = (size_t)(N_PRED + N_SCAN + N_JOIN + N_ENC) * HDIM;
    size_t Aelems = (size_t)N_COL * HDIM;
    if (sumP > Aelems) Aelems = sumP;
    size_t Belems = (size_t)N_FILT * HDIM;

    int maxN = N_FILT;
    if (N_PRED > maxN) maxN = N_PRED;
    if (N_SCAN > maxN) maxN = N_SCAN;
    if (N_JOIN > maxN) maxN = N_JOIN;
    if (N_ENC  > maxN) maxN = N_ENC;
    int maxE = E_CF;
    if (E_FP > maxE) maxE = E_FP;
    if (E_PS > maxE) maxE = E_PS;
    if (E_SJ > maxE) maxE = E_SJ;
    if (E_JE > maxE) maxE = E_JE;

    const int W1P_TOT = 5 * 2 * HDIM * HDIM;   // 163840 bf16
    const int W2P_TOT = 5 * HDIM * HDIM;       //  81920 bf16
    const int WEP_TOT = 6 * FIN * HDIM;        //  24576 bf16
    const int WFP_TOT = HDIM * HDIM;           //  16384 bf16

    size_t aB    = ((Aelems * 2) + 255) & ~(size_t)255;
    size_t bB    = ((Belems * 2) + 255) & ~(size_t)255;
    size_t intB  = (((size_t)maxN * 4) + 255) & ~(size_t)255;
    size_t eidxB = (((size_t)maxE * 4) + 255) & ~(size_t)255;
    size_t wpB   = (((size_t)(W1P_TOT + W2P_TOT + WEP_TOT + WFP_TOT) * 2) + 255) & ~(size_t)255;
    size_t need  = aB + bB + 3 * intB + eidxB + wpB + 8192;

    if (!d_ws || ws_size < need) {
        float val = 1.0e6f + (float)(ws_size >> 20);
        sentinel_kernel<<<dim3((out_size + 255) / 256), dim3(256), 0, stream>>>(
            (float*)d_out, out_size, val);
        return;
    }

    char* base = (char*)d_ws;
    bf16t* A    = (bf16t*)base;                       base += aB;
    bf16t* B    = (bf16t*)base;                       base += bB;
    int* deg    = (int*)base;                         base += intB;
    int* start  = (int*)base;                         base += intB;
    int* cursor = (int*)base;                         base += intB;
    int* eidx   = (int*)base;                         base += eidxB;
    bf16t* W1P  = (bf16t*)base;                       base += (size_t)W1P_TOT * 2;
    bf16t* W2P  = (bf16t*)base;                       base += (size_t)W2P_TOT * 2;
    bf16t* WEP  = (bf16t*)base;                       base += (size_t)WEP_TOT * 2;
    bf16t* WFP  = (bf16t*)base;                       base += (size_t)WFP_TOT * 2;
    int* bsum   = (int*)(((size_t)base + 255) & ~(size_t)255);

    bf16t* h_col  = A;                                 // dead after level 0
    bf16t* h_filt = B;
    bf16t* h_pred = A;
    bf16t* h_scan = A + (size_t)N_PRED * HDIM;
    bf16t* h_join = A + (size_t)(N_PRED + N_SCAN) * HDIM;
    bf16t* h_enc  = A + (size_t)(N_PRED + N_SCAN + N_JOIN) * HDIM;

    const dim3 blk(256);

    // ---- weight repacks ----
    pack_w1_kernel<<<dim3((W1P_TOT + 255) / 256), blk, 0, stream>>>(W1t, W1P, W1P_TOT);
    pack_w2_kernel<<<dim3((W2P_TOT + 255) / 256), blk, 0, stream>>>(W2t, W2P, W2P_TOT);
    pack_we_kernel<<<dim3((WEP_TOT + 255) / 256), blk, 0, stream>>>(W_enc, WEP, WEP_TOT);
    pack_w2_kernel<<<dim3((WFP_TOT + 255) / 256), blk, 0, stream>>>(Wf1, WFP, WFP_TOT);

    // ---- h_col encoder ----
    enc_mfma_kernel<<<dim3((N_COL + 63) / 64), blk, 0, stream>>>(
        x_col, WEP, b_enc, h_col, N_COL);

    // ---- level 0: column -> filter ----
    build_csr(src_cf, dst_cf, E_CF, N_FILT, deg, start, cursor, eidx, bsum, stream);
    fused_combine_kernel<<<dim3((N_FILT + 63) / 64), blk, 0, stream>>>(
        x_filt, WEP + 1 * FIN * HDIM, b_enc + 1 * HDIM,
        h_col, eidx, start, deg,
        W1P, b1t, W2P, b2t, h_filt, N_FILT);

    // ---- level 1: filter -> pred ----
    build_csr(src_fp, dst_fp, E_FP, N_PRED, deg, start, cursor, eidx, bsum, stream);
    fused_combine_kernel<<<dim3((N_PRED + 63) / 64), blk, 0, stream>>>(
        x_pred, WEP + 2 * FIN * HDIM, b_enc + 2 * HDIM,
        h_filt, eidx, start, deg,
        W1P + 1 * 2 * HDIM * HDIM, b1t + 1 * HDIM,
        W2P + 1 * HDIM * HDIM, b2t + 1 * HDIM, h_pred, N_PRED);

    // ---- level 2: pred -> scan ----
    build_csr(src_ps, dst_ps, E_PS, N_SCAN, deg, start, cursor, eidx, bsum, stream);
    fused_combine_kernel<<<dim3((N_SCAN + 63) / 64), blk, 0, stream>>>(
        x_scan, WEP + 3 * FIN * HDIM, b_enc + 3 * HDIM,
        h_pred, eidx, start, deg,
        W1P + 2 * 2 * HDIM * HDIM, b1t + 2 * HDIM,
        W2P + 2 * HDIM * HDIM, b2t + 2 * HDIM, h_scan, N_SCAN);

    // ---- level 3: scan -> join ----
    build_csr(src_sj, dst_sj, E_SJ, N_JOIN, deg, start, cursor, eidx, bsum, stream);
    fused_combine_kernel<<<dim3((N_JOIN + 63) / 64), blk, 0, stream>>>(
        x_join, WEP + 4 * FIN * HDIM, b_enc + 4 * HDIM,
        h_scan, eidx, start, deg,
        W1P + 3 * 2 * HDIM * HDIM, b1t + 3 * HDIM,
        W2P + 3 * HDIM * HDIM, b2t + 3 * HDIM, h_join, N_JOIN);

    // ---- level 4: join -> encode ----
    build_csr(src_je, dst_je, E_JE, N_ENC, deg, start, cursor, eidx, bsum, stream);
    fused_combine_kernel<<<dim3((N_ENC + 63) / 64), blk, 0, stream>>>(
        x_enc, WEP + 5 * FIN * HDIM, b_enc + 5 * HDIM,
        h_join, eidx, start, deg,
        W1P + 4 * 2 * HDIM * HDIM, b1t + 4 * HDIM,
        W2P + 4 * HDIM * HDIM, b2t + 4 * HDIM, h_enc, N_ENC);

    // ---- fused final MLP + projection ----
    finale_kernel<<<dim3((N_ENC + 63) / 64), blk, 0, stream>>>(
        h_enc, WFP, bf1, Wf2, bf2, (float*)d_out, N_ENC);
}

// Round 7
// 617.597 us; speedup vs baseline: 1.0362x; 1.0362x over previous
//
#include <hip/hip_runtime.h>
#include <hip/hip_bf16.h>

#define HDIM 128
#define FIN  32

typedef __hip_bfloat16 bf16t;
using bf16x8 = __attribute__((ext_vector_type(8))) short;
using f32x4  = __attribute__((ext_vector_type(4))) float;

__device__ __forceinline__ float reluf(float x) { return x > 0.f ? x : 0.f; }

__device__ __forceinline__ unsigned short f2bf(float f) {
    unsigned int b = __float_as_uint(f);
    b += 0x7FFFu + ((b >> 16) & 1u);       // round-to-nearest-even
    return (unsigned short)(b >> 16);
}
__device__ __forceinline__ float bf2f(unsigned short u) {
    return __uint_as_float(((unsigned int)u) << 16);
}

__device__ __forceinline__ float4 ld4(const bf16t* p) {
    ushort4 u = *(const ushort4*)p;
    return make_float4(bf2f(u.x), bf2f(u.y), bf2f(u.z), bf2f(u.w));
}
__device__ __forceinline__ void st4(bf16t* p, float4 v) {
    ushort4 u;
    u.x = f2bf(v.x); u.y = f2bf(v.y); u.z = f2bf(v.z); u.w = f2bf(v.w);
    *(ushort4*)p = u;
}

// ======================= CSR construction ===================================
__global__ __launch_bounds__(256) void hist_kernel(
    const int* __restrict__ dst, int* __restrict__ deg, int E)
{
    int i = blockIdx.x * 256 + threadIdx.x;
    if (i < E) atomicAdd(&deg[dst[i]], 1);
}

__global__ __launch_bounds__(256) void scan_blocks_kernel(
    const int* __restrict__ deg, int* __restrict__ start,
    int* __restrict__ bsum, int N)
{
    __shared__ int s[256];
    const int t = threadIdx.x;
    const int base = blockIdx.x * 1024;
    int v[4], tsum = 0;
    #pragma unroll
    for (int i = 0; i < 4; ++i) {
        int idx = base + t * 4 + i;
        v[i] = (idx < N) ? deg[idx] : 0;
        tsum += v[i];
    }
    s[t] = tsum; __syncthreads();
    for (int off = 1; off < 256; off <<= 1) {
        int x = (t >= off) ? s[t - off] : 0;
        __syncthreads();
        s[t] += x;
        __syncthreads();
    }
    if (t == 255) bsum[blockIdx.x] = s[255];
    int run = s[t] - tsum;
    #pragma unroll
    for (int i = 0; i < 4; ++i) {
        int idx = base + t * 4 + i;
        if (idx < N) start[idx] = run;
        run += v[i];
    }
}

__global__ __launch_bounds__(256) void scan_top_kernel(int* __restrict__ bsum, int B)
{
    __shared__ int s[256];
    const int t = threadIdx.x;
    int v[4], tsum = 0;
    #pragma unroll
    for (int i = 0; i < 4; ++i) {
        int idx = t * 4 + i;
        v[i] = (idx < B) ? bsum[idx] : 0;
        tsum += v[i];
    }
    s[t] = tsum; __syncthreads();
    for (int off = 1; off < 256; off <<= 1) {
        int x = (t >= off) ? s[t - off] : 0;
        __syncthreads();
        s[t] += x;
        __syncthreads();
    }
    int run = s[t] - tsum;
    #pragma unroll
    for (int i = 0; i < 4; ++i) {
        int idx = t * 4 + i;
        if (idx < B) bsum[idx] = run;
        run += v[i];
    }
}

__global__ __launch_bounds__(256) void scan_add_kernel(
    int* __restrict__ start, int* __restrict__ cursor,
    const int* __restrict__ bsum, int N)
{
    int i = blockIdx.x * 256 + threadIdx.x;
    if (i < N) {
        int v = start[i] + bsum[i >> 10];
        start[i]  = v;
        cursor[i] = v;
    }
}

__global__ __launch_bounds__(256) void fill_kernel(
    const int* __restrict__ src, const int* __restrict__ dst,
    int* __restrict__ cursor, int* __restrict__ eidx, int E)
{
    int i = blockIdx.x * 256 + threadIdx.x;
    if (i < E) {
        int d = dst[i];
        int p = atomicAdd(&cursor[d], 1);
        eidx[p] = src[i];
    }
}

// ======================= gather-based segment sum ===========================
__global__ __launch_bounds__(256) void gather_kernel(
    const bf16t* __restrict__ h, const int* __restrict__ eidx,
    const int* __restrict__ start, const int* __restrict__ deg,
    bf16t* __restrict__ msg, int N)
{
    int r = blockIdx.x * 8 + (threadIdx.x >> 5);
    if (r >= N) return;
    int lane = threadIdx.x & 31;
    int s0 = start[r], cnt = deg[r];
    float4 acc = make_float4(0.f, 0.f, 0.f, 0.f);
    for (int j = s0; j < s0 + cnt; ++j) {
        int s = eidx[j];
        float4 v = ld4(&h[(size_t)s * HDIM + lane * 4]);
        acc.x += v.x; acc.y += v.y; acc.z += v.z; acc.w += v.w;
    }
    st4(&msg[(size_t)r * HDIM + lane * 4], acc);
}

// ======================= weight repack (MFMA A-fragment order) ==============
// A-frag: lane l, elem j holds A[m = mt*16 + (l&15)][k = kc*32 + (l>>4)*8 + j]
// with A = W^T, i.e. value W[k][m], stored at P[((kc*NMT + mt)*64 + l)*8 + j].
__global__ __launch_bounds__(256) void pack_w1_kernel(
    const float* __restrict__ W1t, bf16t* __restrict__ W1P, int total)
{
    int q = blockIdx.x * 256 + threadIdx.x;
    if (q >= total) return;
    int L = q >> 15;                 // 32768 per level (K=256, 8 kc x 8 mt)
    int r = q & 32767;
    int j = r & 7, l = (r >> 3) & 63, mt = (r >> 9) & 7, kc = (r >> 12) & 7;
    float v = W1t[(size_t)L * 2 * HDIM * HDIM +
                  (size_t)(kc * 32 + ((l >> 4) & 3) * 8 + j) * HDIM + mt * 16 + (l & 15)];
    *(unsigned short*)&W1P[q] = f2bf(v);
}

__global__ __launch_bounds__(256) void pack_w2_kernel(
    const float* __restrict__ W2t, bf16t* __restrict__ W2P, int total)
{
    int q = blockIdx.x * 256 + threadIdx.x;
    if (q >= total) return;
    int L = q >> 14;                 // 16384 per level (K=128, 4 kc x 8 mt)
    int r = q & 16383;
    int j = r & 7, l = (r >> 3) & 63, mt = (r >> 9) & 7, kc = (r >> 12) & 3;
    float v = W2t[(size_t)L * HDIM * HDIM +
                  (size_t)(kc * 32 + ((l >> 4) & 3) * 8 + j) * HDIM + mt * 16 + (l & 15)];
    *(unsigned short*)&W2P[q] = f2bf(v);
}

// K=32 encoder weights: 6 encoders x (8 mt x 64 l x 8 j) = 6*4096
__global__ __launch_bounds__(256) void pack_we_kernel(
    const float* __restrict__ We, bf16t* __restrict__ WeP, int total)
{
    int q = blockIdx.x * 256 + threadIdx.x;
    if (q >= total) return;
    int enc = q >> 12;
    int r = q & 4095;
    int j = r & 7, l = (r >> 3) & 63, mt = (r >> 9) & 7;
    int k = ((l >> 4) & 3) * 8 + j;
    float v = We[(size_t)enc * FIN * HDIM + (size_t)k * HDIM + mt * 16 + (l & 15)];
    *(unsigned short*)&WeP[q] = f2bf(v);
}

// ======================= MFMA encoder =======================================
__global__ __launch_bounds__(256) void enc_mfma_kernel(
    const float* __restrict__ x, const bf16t* __restrict__ WP,
    const float* __restrict__ b, bf16t* __restrict__ h, int N)
{
    __shared__ bf16t x_s[64 * 36];
    const int tid  = threadIdx.x;
    const int row0 = blockIdx.x * 64;
    const int wave = tid >> 6, lane = tid & 63;
    const int l15 = lane & 15, l16 = lane >> 4;

    #pragma unroll
    for (int i = 0; i < 2; ++i) {
        int f = tid + i * 256;
        int r = f >> 3, c4 = f & 7;
        int row = row0 + r; if (row >= N) row = N - 1;
        float4 v = *(const float4*)&x[(size_t)row * FIN + c4 * 4];
        ushort4 u;
        u.x = f2bf(v.x); u.y = f2bf(v.y); u.z = f2bf(v.z); u.w = f2bf(v.w);
        *(ushort4*)&x_s[r * 36 + c4 * 4] = u;
    }
    __syncthreads();

    f32x4 acc[2][4];
    #pragma unroll
    for (int m = 0; m < 2; ++m)
        #pragma unroll
        for (int n = 0; n < 4; ++n)
            #pragma unroll
            for (int i = 0; i < 4; ++i) acc[m][n][i] = 0.f;

    bf16x8 a[2], bb[4];
    #pragma unroll
    for (int m = 0; m < 2; ++m)
        a[m] = *(const bf16x8*)&WP[(((wave * 2 + m)) * 64 + lane) * 8];
    #pragma unroll
    for (int n = 0; n < 4; ++n)
        bb[n] = *(const bf16x8*)&x_s[(n * 16 + l15) * 36 + l16 * 8];
    #pragma unroll
    for (int m = 0; m < 2; ++m)
        #pragma unroll
        for (int n = 0; n < 4; ++n)
            acc[m][n] = __builtin_amdgcn_mfma_f32_16x16x32_bf16(a[m], bb[n], acc[m][n], 0, 0, 0);

    #pragma unroll
    for (int m = 0; m < 2; ++m) {
        int mt = wave * 2 + m;
        float4 bv = *(const float4*)&b[mt * 16 + l16 * 4];
        #pragma unroll
        for (int n = 0; n < 4; ++n) {
            int row = row0 + n * 16 + l15;
            if (row < N) {
                ushort4 u;
                u.x = f2bf(reluf(acc[m][n][0] + bv.x));
                u.y = f2bf(reluf(acc[m][n][1] + bv.y));
                u.z = f2bf(reluf(acc[m][n][2] + bv.z));
                u.w = f2bf(reluf(acc[m][n][3] + bv.w));
                *(ushort4*)&h[(size_t)row * HDIM + mt * 16 + l16 * 4] = u;
            }
        }
    }
}

// ======================= MFMA combine (direct-global B-frags) ===============
// z1 = relu([hd|msg] @ W1 + b1); hd = relu(z1 @ W2 + b2).
// GEMM1 B-fragments are loaded straight from hd/msg (16B/lane, 64B-coalesced,
// each act row read exactly once per block) — no act staging, LDS = z_s only.
#define Z_STRIDE 136   // 128 + 8 bf16 pad
__global__ __launch_bounds__(256) void combine_mfma_kernel(
    bf16t* __restrict__ hd, const bf16t* __restrict__ msg,
    const bf16t* __restrict__ W1P, const float* __restrict__ b1,
    const bf16t* __restrict__ W2P, const float* __restrict__ b2, int N)
{
    __shared__ bf16t z_s[64 * Z_STRIDE];       // 17,408 B

    const int tid  = threadIdx.x;
    const int row0 = blockIdx.x * 64;
    const int wave = tid >> 6, lane = tid & 63;
    const int l15 = lane & 15, l16 = lane >> 4;

    // per-lane B-frag row indices (clamped)
    int brow[4];
    #pragma unroll
    for (int n = 0; n < 4; ++n) {
        int r = row0 + n * 16 + l15;
        brow[n] = (r < N) ? r : (N - 1);
    }

    // ---- GEMM1: K=256 over [hd | msg], B-frags direct from global ----
    f32x4 acc1[2][4];
    #pragma unroll
    for (int m = 0; m < 2; ++m)
        #pragma unroll
        for (int n = 0; n < 4; ++n)
            #pragma unroll
            for (int i = 0; i < 4; ++i) acc1[m][n][i] = 0.f;

    #pragma unroll
    for (int kc = 0; kc < 8; ++kc) {
        const bf16t* srcp = (kc < 4) ? hd : msg;
        const int koff = (kc & 3) * 32 + l16 * 8;
        bf16x8 a[2], b[4];
        #pragma unroll
        for (int m = 0; m < 2; ++m) {
            int mt = wave * 2 + m;
            a[m] = *(const bf16x8*)&W1P[((kc * 8 + mt) * 64 + lane) * 8];
        }
        #pragma unroll
        for (int n = 0; n < 4; ++n)
            b[n] = *(const bf16x8*)&srcp[(size_t)brow[n] * HDIM + koff];
        #pragma unroll
        for (int m = 0; m < 2; ++m)
            #pragma unroll
            for (int n = 0; n < 4; ++n)
                acc1[m][n] = __builtin_amdgcn_mfma_f32_16x16x32_bf16(a[m], b[n], acc1[m][n], 0, 0, 0);
    }

    // ---- z1 = relu(acc1 + b1) -> z_s (bf16) ----
    #pragma unroll
    for (int m = 0; m < 2; ++m) {
        int mt = wave * 2 + m;
        float4 bb = *(const float4*)&b1[mt * 16 + l16 * 4];
        #pragma unroll
        for (int n = 0; n < 4; ++n) {
            int zrow = n * 16 + l15;
            ushort4 u;
            u.x = f2bf(reluf(acc1[m][n][0] + bb.x));
            u.y = f2bf(reluf(acc1[m][n][1] + bb.y));
            u.z = f2bf(reluf(acc1[m][n][2] + bb.z));
            u.w = f2bf(reluf(acc1[m][n][3] + bb.w));
            *(ushort4*)&z_s[zrow * Z_STRIDE + mt * 16 + l16 * 4] = u;
        }
    }
    __syncthreads();

    // ---- GEMM2: K=128 over z1 (LDS) ----
    f32x4 acc2[2][4];
    #pragma unroll
    for (int m = 0; m < 2; ++m)
        #pragma unroll
        for (int n = 0; n < 4; ++n)
            #pragma unroll
            for (int i = 0; i < 4; ++i) acc2[m][n][i] = 0.f;

    #pragma unroll
    for (int kc = 0; kc < 4; ++kc) {
        bf16x8 a[2], b[4];
        #pragma unroll
        for (int m = 0; m < 2; ++m) {
            int mt = wave * 2 + m;
            a[m] = *(const bf16x8*)&W2P[((kc * 8 + mt) * 64 + lane) * 8];
        }
        #pragma unroll
        for (int n = 0; n < 4; ++n)
            b[n] = *(const bf16x8*)&z_s[(n * 16 + l15) * Z_STRIDE + kc * 32 + l16 * 8];
        #pragma unroll
        for (int m = 0; m < 2; ++m)
            #pragma unroll
            for (int n = 0; n < 4; ++n)
                acc2[m][n] = __builtin_amdgcn_mfma_f32_16x16x32_bf16(a[m], b[n], acc2[m][n], 0, 0, 0);
    }

    #pragma unroll
    for (int m = 0; m < 2; ++m) {
        int mt = wave * 2 + m;
        float4 bb = *(const float4*)&b2[mt * 16 + l16 * 4];
        #pragma unroll
        for (int n = 0; n < 4; ++n) {
            int row = row0 + n * 16 + l15;
            if (row < N) {
                ushort4 u;
                u.x = f2bf(reluf(acc2[m][n][0] + bb.x));
                u.y = f2bf(reluf(acc2[m][n][1] + bb.y));
                u.z = f2bf(reluf(acc2[m][n][2] + bb.z));
                u.w = f2bf(reluf(acc2[m][n][3] + bb.w));
                *(ushort4*)&hd[(size_t)row * HDIM + mt * 16 + l16 * 4] = u;
            }
        }
    }
}

// ======================= fused final MLP + rowdot ===========================
__global__ __launch_bounds__(256) void finale_kernel(
    const bf16t* __restrict__ he, const bf16t* __restrict__ W1P,
    const float* __restrict__ b1, const float* __restrict__ w2,
    const float* __restrict__ b2, float* __restrict__ out, int N)
{
    __shared__ float o_s[64];

    const int tid  = threadIdx.x;
    const int row0 = blockIdx.x * 64;
    const int wave = tid >> 6, lane = tid & 63;
    const int l15 = lane & 15, l16 = lane >> 4;

    if (tid < 64) o_s[tid] = 0.f;
    __syncthreads();

    int brow[4];
    #pragma unroll
    for (int n = 0; n < 4; ++n) {
        int r = row0 + n * 16 + l15;
        brow[n] = (r < N) ? r : (N - 1);
    }

    f32x4 acc[2][4];
    #pragma unroll
    for (int m = 0; m < 2; ++m)
        #pragma unroll
        for (int n = 0; n < 4; ++n)
            #pragma unroll
            for (int i = 0; i < 4; ++i) acc[m][n][i] = 0.f;

    #pragma unroll
    for (int kc = 0; kc < 4; ++kc) {
        const int koff = kc * 32 + l16 * 8;
        bf16x8 a[2], b[4];
        #pragma unroll
        for (int m = 0; m < 2; ++m) {
            int mt = wave * 2 + m;
            a[m] = *(const bf16x8*)&W1P[((kc * 8 + mt) * 64 + lane) * 8];
        }
        #pragma unroll
        for (int n = 0; n < 4; ++n)
            b[n] = *(const bf16x8*)&he[(size_t)brow[n] * HDIM + koff];
        #pragma unroll
        for (int m = 0; m < 2; ++m)
            #pragma unroll
            for (int n = 0; n < 4; ++n)
                acc[m][n] = __builtin_amdgcn_mfma_f32_16x16x32_bf16(a[m], b[n], acc[m][n], 0, 0, 0);
    }

    float s[4] = {0.f, 0.f, 0.f, 0.f};
    #pragma unroll
    for (int m = 0; m < 2; ++m) {
        int mt = wave * 2 + m;
        float4 bb = *(const float4*)&b1[mt * 16 + l16 * 4];
        float4 ww = *(const float4*)&w2[mt * 16 + l16 * 4];
        #pragma unroll
        for (int n = 0; n < 4; ++n) {
            s[n] += reluf(acc[m][n][0] + bb.x) * ww.x
                  + reluf(acc[m][n][1] + bb.y) * ww.y
                  + reluf(acc[m][n][2] + bb.z) * ww.z
                  + reluf(acc[m][n][3] + bb.w) * ww.w;
        }
    }
    #pragma unroll
    for (int n = 0; n < 4; ++n) {
        s[n] += __shfl_xor(s[n], 16, 64);
        s[n] += __shfl_xor(s[n], 32, 64);
        if (l16 == 0) atomicAdd(&o_s[n * 16 + l15], s[n]);
    }
    __syncthreads();
    if (tid < 64) {
        int row = row0 + tid;
        if (row < N) out[row] = o_s[tid] + b2[0];
    }
}

__global__ __launch_bounds__(256) void sentinel_kernel(float* out, int n, float val)
{
    int i = blockIdx.x * 256 + threadIdx.x;
    if (i < n) out[i] = (i == 0) ? val : 0.f;
}

// ---------------------------------------------------------------------------
static void build_csr(const int* src, const int* dst, int E, int N,
                      int* deg, int* start, int* cursor, int* eidx, int* bsum,
                      hipStream_t stream)
{
    const dim3 blk(256);
    hipMemsetAsync(deg, 0, (size_t)N * sizeof(int), stream);
    hist_kernel<<<dim3((E + 255) / 256), blk, 0, stream>>>(dst, deg, E);
    int B = (N + 1023) / 1024;
    scan_blocks_kernel<<<dim3(B), blk, 0, stream>>>(deg, start, bsum, N);
    scan_top_kernel<<<dim3(1), blk, 0, stream>>>(bsum, B);
    scan_add_kernel<<<dim3((N + 255) / 256), blk, 0, stream>>>(start, cursor, bsum, N);
    fill_kernel<<<dim3((E + 255) / 256), blk, 0, stream>>>(src, dst, cursor, eidx, E);
}

extern "C" void kernel_launch(void* const* d_in, const int* in_sizes, int n_in,
                              void* d_out, int out_size, void* d_ws, size_t ws_size,
                              hipStream_t stream)
{
    const float* x_col  = (const float*)d_in[0];
    const float* x_filt = (const float*)d_in[1];
    const float* x_pred = (const float*)d_in[2];
    const float* x_scan = (const float*)d_in[3];
    const float* x_join = (const float*)d_in[4];
    const float* x_enc  = (const float*)d_in[5];
    const float* W_enc  = (const float*)d_in[6];
    const float* b_enc  = (const float*)d_in[7];
    const float* W1t    = (const float*)d_in[8];
    const float* b1t    = (const float*)d_in[9];
    const float* W2t    = (const float*)d_in[10];
    const float* b2t    = (const float*)d_in[11];
    const float* Wf1    = (const float*)d_in[12];
    const float* bf1    = (const float*)d_in[13];
    const float* Wf2    = (const float*)d_in[14];
    const float* bf2    = (const float*)d_in[15];
    const int* src_cf = (const int*)d_in[16];
    const int* dst_cf = (const int*)d_in[17];
    const int* src_fp = (const int*)d_in[18];
    const int* dst_fp = (const int*)d_in[19];
    const int* src_ps = (const int*)d_in[20];
    const int* dst_ps = (const int*)d_in[21];
    const int* src_sj = (const int*)d_in[22];
    const int* dst_sj = (const int*)d_in[23];
    const int* src_je = (const int*)d_in[24];
    const int* dst_je = (const int*)d_in[25];

    const int N_COL  = in_sizes[0] / FIN;
    const int N_FILT = in_sizes[1] / FIN;
    const int N_PRED = in_sizes[2] / FIN;
    const int N_SCAN = in_sizes[3] / FIN;
    const int N_JOIN = in_sizes[4] / FIN;
    const int N_ENC  = in_sizes[5] / FIN;
    const int E_CF = in_sizes[16];
    const int E_FP = in_sizes[18];
    const int E_PS = in_sizes[20];
    const int E_SJ = in_sizes[22];
    const int E_JE = in_sizes[24];

    // ---- workspace layout (round-5 proven aliasing) ----
    size_t Mf = 0;
    {
        size_t c;
        c = (size_t)N_FILT * HDIM; if (c > Mf) Mf = c;
        c = (size_t)N_PRED * HDIM; if (c > Mf) Mf = c;
        c = (size_t)N_SCAN * HDIM; if (c > Mf) Mf = c;
        c = (size_t)N_JOIN * HDIM; if (c > Mf) Mf = c;
        c = (size_t)N_ENC  * HDIM; if (c > Mf) Mf = c;
    }
    size_t Hf = (size_t)N_COL * HDIM;
    { size_t c = (size_t)(N_FILT + N_PRED) * HDIM; if (c > Hf) Hf = c; }
    { size_t c = (size_t)(N_SCAN + N_JOIN + N_ENC + N_PRED) * HDIM; if (c > Hf) Hf = c; }

    int maxN = N_FILT;
    if (N_PRED > maxN) maxN = N_PRED;
    if (N_SCAN > maxN) maxN = N_SCAN;
    if (N_JOIN > maxN) maxN = N_JOIN;
    if (N_ENC  > maxN) maxN = N_ENC;
    int maxE = E_CF;
    if (E_FP > maxE) maxE = E_FP;
    if (E_PS > maxE) maxE = E_PS;
    if (E_SJ > maxE) maxE = E_SJ;
    if (E_JE > maxE) maxE = E_JE;

    const int W1P_TOT = 5 * 2 * HDIM * HDIM;   // 163840 bf16
    const int W2P_TOT = 5 * HDIM * HDIM;       //  81920 bf16
    const int WEP_TOT = 6 * FIN * HDIM;        //  24576 bf16
    const int WFP_TOT = HDIM * HDIM;           //  16384 bf16

    size_t msgB  = ((Mf * 2) + 255) & ~(size_t)255;
    size_t hB    = ((Hf * 2) + 255) & ~(size_t)255;
    size_t intB  = (((size_t)maxN * 4) + 255) & ~(size_t)255;
    size_t eidxB = (((size_t)maxE * 4) + 255) & ~(size_t)255;
    size_t wpB   = (((size_t)(W1P_TOT + W2P_TOT + WEP_TOT + WFP_TOT) * 2) + 255) & ~(size_t)255;
    size_t need  = msgB + hB + 3 * intB + eidxB + wpB + 8192;

    if (!d_ws || ws_size < need) {
        float val = 1.0e6f + (float)(ws_size >> 20);
        sentinel_kernel<<<dim3((out_size + 255) / 256), dim3(256), 0, stream>>>(
            (float*)d_out, out_size, val);
        return;
    }

    char* base = (char*)d_ws;
    bf16t* msg  = (bf16t*)base;                       base += msgB;
    bf16t* H    = (bf16t*)base;                       base += hB;
    int* deg    = (int*)base;                         base += intB;
    int* start  = (int*)base;                         base += intB;
    int* cursor = (int*)base;                         base += intB;
    int* eidx   = (int*)base;                         base += eidxB;
    bf16t* W1P  = (bf16t*)base;                       base += (size_t)W1P_TOT * 2;
    bf16t* W2P  = (bf16t*)base;                       base += (size_t)W2P_TOT * 2;
    bf16t* WEP  = (bf16t*)base;                       base += (size_t)WEP_TOT * 2;
    bf16t* WFP  = (bf16t*)base;                       base += (size_t)WFP_TOT * 2;
    int* bsum   = (int*)(((size_t)base + 255) & ~(size_t)255);

    bf16t* h_col  = H;                                 // dead after gather0
    bf16t* h_filt = H;
    bf16t* h_pred = H + (size_t)N_FILT * HDIM;
    bf16t* h_scan = H;                                 // h_filt dead by then
    bf16t* h_join = H + (size_t)N_SCAN * HDIM;
    bf16t* h_enc  = H + (size_t)(N_SCAN + N_JOIN) * HDIM;

    const dim3 blk(256);

    // ---- weight repacks ----
    pack_w1_kernel<<<dim3((W1P_TOT + 255) / 256), blk, 0, stream>>>(W1t, W1P, W1P_TOT);
    pack_w2_kernel<<<dim3((W2P_TOT + 255) / 256), blk, 0, stream>>>(W2t, W2P, W2P_TOT);
    pack_we_kernel<<<dim3((WEP_TOT + 255) / 256), blk, 0, stream>>>(W_enc, WEP, WEP_TOT);
    pack_w2_kernel<<<dim3((WFP_TOT + 255) / 256), blk, 0, stream>>>(Wf1, WFP, WFP_TOT);

    // ---- level 0: column -> filter ----
    build_csr(src_cf, dst_cf, E_CF, N_FILT, deg, start, cursor, eidx, bsum, stream);
    enc_mfma_kernel<<<dim3((N_COL + 63) / 64), blk, 0, stream>>>(
        x_col, WEP, b_enc, h_col, N_COL);
    gather_kernel<<<dim3((N_FILT + 7) / 8), blk, 0, stream>>>(
        h_col, eidx, start, deg, msg, N_FILT);
    enc_mfma_kernel<<<dim3((N_FILT + 63) / 64), blk, 0, stream>>>(   // overwrites h_col region
        x_filt, WEP + 1 * FIN * HDIM, b_enc + 1 * HDIM, h_filt, N_FILT);
    combine_mfma_kernel<<<dim3((N_FILT + 63) / 64), blk, 0, stream>>>(
        h_filt, msg, W1P, b1t, W2P, b2t, N_FILT);

    // ---- level 1: filter -> pred ----
    build_csr(src_fp, dst_fp, E_FP, N_PRED, deg, start, cursor, eidx, bsum, stream);
    gather_kernel<<<dim3((N_PRED + 7) / 8), blk, 0, stream>>>(
        h_filt, eidx, start, deg, msg, N_PRED);
    enc_mfma_kernel<<<dim3((N_PRED + 63) / 64), blk, 0, stream>>>(
        x_pred, WEP + 2 * FIN * HDIM, b_enc + 2 * HDIM, h_pred, N_PRED);
    combine_mfma_kernel<<<dim3((N_PRED + 63) / 64), blk, 0, stream>>>(
        h_pred, msg, W1P + 1 * 2 * HDIM * HDIM, b1t + 1 * HDIM,
        W2P + 1 * HDIM * HDIM, b2t + 1 * HDIM, N_PRED);

    // ---- level 2: pred -> scan ----
    build_csr(src_ps, dst_ps, E_PS, N_SCAN, deg, start, cursor, eidx, bsum, stream);
    gather_kernel<<<dim3((N_SCAN + 7) / 8), blk, 0, stream>>>(
        h_pred, eidx, start, deg, msg, N_SCAN);
    enc_mfma_kernel<<<dim3((N_SCAN + 63) / 64), blk, 0, stream>>>(
        x_scan, WEP + 3 * FIN * HDIM, b_enc + 3 * HDIM, h_scan, N_SCAN);
    combine_mfma_kernel<<<dim3((N_SCAN + 63) / 64), blk, 0, stream>>>(
        h_scan, msg, W1P + 2 * 2 * HDIM * HDIM, b1t + 2 * HDIM,
        W2P + 2 * HDIM * HDIM, b2t + 2 * HDIM, N_SCAN);

    // ---- level 3: scan -> join ----
    build_csr(src_sj, dst_sj, E_SJ, N_JOIN, deg, start, cursor, eidx, bsum, stream);
    gather_kernel<<<dim3((N_JOIN + 7) / 8), blk, 0, stream>>>(
        h_scan, eidx, start, deg, msg, N_JOIN);
    enc_mfma_kernel<<<dim3((N_JOIN + 63) / 64), blk, 0, stream>>>(
        x_join, WEP + 4 * FIN * HDIM, b_enc + 4 * HDIM, h_join, N_JOIN);
    combine_mfma_kernel<<<dim3((N_JOIN + 63) / 64), blk, 0, stream>>>(
        h_join, msg, W1P + 3 * 2 * HDIM * HDIM, b1t + 3 * HDIM,
        W2P + 3 * HDIM * HDIM, b2t + 3 * HDIM, N_JOIN);

    // ---- level 4: join -> encode ----
    build_csr(src_je, dst_je, E_JE, N_ENC, deg, start, cursor, eidx, bsum, stream);
    gather_kernel<<<dim3((N_ENC + 7) / 8), blk, 0, stream>>>(
        h_join, eidx, start, deg, msg, N_ENC);
    enc_mfma_kernel<<<dim3((N_ENC + 63) / 64), blk, 0, stream>>>(
        x_enc, WEP + 5 * FIN * HDIM, b_enc + 5 * HDIM, h_enc, N_ENC);
    combine_mfma_kernel<<<dim3((N_ENC + 63) / 64), blk, 0, stream>>>(
        h_enc, msg, W1P + 4 * 2 * HDIM * HDIM, b1t + 4 * HDIM,
        W2P + 4 * HDIM * HDIM, b2t + 4 * HDIM, N_ENC);

    // ---- fused final MLP + projection ----
    finale_kernel<<<dim3((N_ENC + 63) / 64), blk, 0, stream>>>(
        h_enc, WFP, bf1, Wf2, bf2, (float*)d_out, N_ENC);
}

// Round 8
// 501.126 us; speedup vs baseline: 1.2771x; 1.2324x over previous
//
#include <hip/hip_runtime.h>
#include <hip/hip_bf16.h>

#define HDIM 128
#define FIN  32

typedef __hip_bfloat16 bf16t;
using bf16x8 = __attribute__((ext_vector_type(8))) short;
using f32x4  = __attribute__((ext_vector_type(4))) float;

__device__ __forceinline__ float reluf(float x) { return x > 0.f ? x : 0.f; }

__device__ __forceinline__ unsigned short f2bf(float f) {
    unsigned int b = __float_as_uint(f);
    b += 0x7FFFu + ((b >> 16) & 1u);       // round-to-nearest-even
    return (unsigned short)(b >> 16);
}
__device__ __forceinline__ float bf2f(unsigned short u) {
    return __uint_as_float(((unsigned int)u) << 16);
}

__device__ __forceinline__ float4 ld4(const bf16t* p) {
    ushort4 u = *(const ushort4*)p;
    return make_float4(bf2f(u.x), bf2f(u.y), bf2f(u.z), bf2f(u.w));
}
__device__ __forceinline__ void st4(bf16t* p, float4 v) {
    ushort4 u;
    u.x = f2bf(v.x); u.y = f2bf(v.y); u.z = f2bf(v.z); u.w = f2bf(v.w);
    *(ushort4*)p = u;
}

// ======================= CSR construction ===================================
__global__ __launch_bounds__(256) void hist_kernel(
    const int* __restrict__ dst, int* __restrict__ deg, int E)
{
    int i = blockIdx.x * 256 + threadIdx.x;
    if (i < E) atomicAdd(&deg[dst[i]], 1);
}

__global__ __launch_bounds__(256) void scan_blocks_kernel(
    const int* __restrict__ deg, int* __restrict__ start,
    int* __restrict__ bsum, int N)
{
    __shared__ int s[256];
    const int t = threadIdx.x;
    const int base = blockIdx.x * 1024;
    int v[4], tsum = 0;
    #pragma unroll
    for (int i = 0; i < 4; ++i) {
        int idx = base + t * 4 + i;
        v[i] = (idx < N) ? deg[idx] : 0;
        tsum += v[i];
    }
    s[t] = tsum; __syncthreads();
    for (int off = 1; off < 256; off <<= 1) {
        int x = (t >= off) ? s[t - off] : 0;
        __syncthreads();
        s[t] += x;
        __syncthreads();
    }
    if (t == 255) bsum[blockIdx.x] = s[255];
    int run = s[t] - tsum;
    #pragma unroll
    for (int i = 0; i < 4; ++i) {
        int idx = base + t * 4 + i;
        if (idx < N) start[idx] = run;
        run += v[i];
    }
}

__global__ __launch_bounds__(256) void scan_top_kernel(int* __restrict__ bsum, int B)
{
    __shared__ int s[256];
    const int t = threadIdx.x;
    int v[4], tsum = 0;
    #pragma unroll
    for (int i = 0; i < 4; ++i) {
        int idx = t * 4 + i;
        v[i] = (idx < B) ? bsum[idx] : 0;
        tsum += v[i];
    }
    s[t] = tsum; __syncthreads();
    for (int off = 1; off < 256; off <<= 1) {
        int x = (t >= off) ? s[t - off] : 0;
        __syncthreads();
        s[t] += x;
        __syncthreads();
    }
    int run = s[t] - tsum;
    #pragma unroll
    for (int i = 0; i < 4; ++i) {
        int idx = t * 4 + i;
        if (idx < B) bsum[idx] = run;
        run += v[i];
    }
}

__global__ __launch_bounds__(256) void scan_add_kernel(
    int* __restrict__ start, int* __restrict__ cursor,
    const int* __restrict__ bsum, int N)
{
    int i = blockIdx.x * 256 + threadIdx.x;
    if (i < N) {
        int v = start[i] + bsum[i >> 10];
        start[i]  = v;
        cursor[i] = v;
    }
}

__global__ __launch_bounds__(256) void fill_kernel(
    const int* __restrict__ src, const int* __restrict__ dst,
    int* __restrict__ cursor, int* __restrict__ eidx, int E)
{
    int i = blockIdx.x * 256 + threadIdx.x;
    if (i < E) {
        int d = dst[i];
        int p = atomicAdd(&cursor[d], 1);
        eidx[p] = src[i];
    }
}

// ======================= gather-based segment sum (round-5 proven) ==========
__global__ __launch_bounds__(256) void gather_kernel(
    const bf16t* __restrict__ h, const int* __restrict__ eidx,
    const int* __restrict__ start, const int* __restrict__ deg,
    bf16t* __restrict__ msg, int N)
{
    int r = blockIdx.x * 8 + (threadIdx.x >> 5);
    if (r >= N) return;
    int lane = threadIdx.x & 31;
    int s0 = start[r], cnt = deg[r];
    float4 acc = make_float4(0.f, 0.f, 0.f, 0.f);
    for (int j = s0; j < s0 + cnt; ++j) {
        int s = eidx[j];
        float4 v = ld4(&h[(size_t)s * HDIM + lane * 4]);
        acc.x += v.x; acc.y += v.y; acc.z += v.z; acc.w += v.w;
    }
    st4(&msg[(size_t)r * HDIM + lane * 4], acc);
}

// ======================= weight repack (MFMA A-fragment order) ==============
__global__ __launch_bounds__(256) void pack_w1_kernel(
    const float* __restrict__ W1t, bf16t* __restrict__ W1P, int total)
{
    int q = blockIdx.x * 256 + threadIdx.x;
    if (q >= total) return;
    int L = q >> 15;                 // 32768 per level (K=256, 8 kc x 8 mt)
    int r = q & 32767;
    int j = r & 7, l = (r >> 3) & 63, mt = (r >> 9) & 7, kc = (r >> 12) & 7;
    float v = W1t[(size_t)L * 2 * HDIM * HDIM +
                  (size_t)(kc * 32 + ((l >> 4) & 3) * 8 + j) * HDIM + mt * 16 + (l & 15)];
    *(unsigned short*)&W1P[q] = f2bf(v);
}

__global__ __launch_bounds__(256) void pack_w2_kernel(
    const float* __restrict__ W2t, bf16t* __restrict__ W2P, int total)
{
    int q = blockIdx.x * 256 + threadIdx.x;
    if (q >= total) return;
    int L = q >> 14;                 // 16384 per level (K=128, 4 kc x 8 mt)
    int r = q & 16383;
    int j = r & 7, l = (r >> 3) & 63, mt = (r >> 9) & 7, kc = (r >> 12) & 3;
    float v = W2t[(size_t)L * HDIM * HDIM +
                  (size_t)(kc * 32 + ((l >> 4) & 3) * 8 + j) * HDIM + mt * 16 + (l & 15)];
    *(unsigned short*)&W2P[q] = f2bf(v);
}

// K=32 encoder weights: 6 encoders x (8 mt x 64 l x 8 j)
__global__ __launch_bounds__(256) void pack_we_kernel(
    const float* __restrict__ We, bf16t* __restrict__ WeP, int total)
{
    int q = blockIdx.x * 256 + threadIdx.x;
    if (q >= total) return;
    int enc = q >> 12;
    int r = q & 4095;
    int j = r & 7, l = (r >> 3) & 63, mt = (r >> 9) & 7;
    int k = ((l >> 4) & 3) * 8 + j;
    float v = We[(size_t)enc * FIN * HDIM + (size_t)k * HDIM + mt * 16 + (l & 15)];
    *(unsigned short*)&WeP[q] = f2bf(v);
}

// ======================= MFMA encoder (h_col only) ==========================
__global__ __launch_bounds__(256) void enc_mfma_kernel(
    const float* __restrict__ x, const bf16t* __restrict__ WP,
    const float* __restrict__ b, bf16t* __restrict__ h, int N)
{
    __shared__ bf16t x_s[64 * 36];
    const int tid  = threadIdx.x;
    const int row0 = blockIdx.x * 64;
    const int wave = tid >> 6, lane = tid & 63;
    const int l15 = lane & 15, l16 = lane >> 4;

    #pragma unroll
    for (int i = 0; i < 2; ++i) {
        int f = tid + i * 256;
        int r = f >> 3, c4 = f & 7;
        int row = row0 + r; if (row >= N) row = N - 1;
        float4 v = *(const float4*)&x[(size_t)row * FIN + c4 * 4];
        ushort4 u;
        u.x = f2bf(v.x); u.y = f2bf(v.y); u.z = f2bf(v.z); u.w = f2bf(v.w);
        *(ushort4*)&x_s[r * 36 + c4 * 4] = u;
    }
    __syncthreads();

    f32x4 acc[2][4];
    #pragma unroll
    for (int m = 0; m < 2; ++m)
        #pragma unroll
        for (int n = 0; n < 4; ++n)
            #pragma unroll
            for (int i = 0; i < 4; ++i) acc[m][n][i] = 0.f;

    bf16x8 a[2], bb[4];
    #pragma unroll
    for (int m = 0; m < 2; ++m)
        a[m] = *(const bf16x8*)&WP[(((wave * 2 + m)) * 64 + lane) * 8];
    #pragma unroll
    for (int n = 0; n < 4; ++n)
        bb[n] = *(const bf16x8*)&x_s[(n * 16 + l15) * 36 + l16 * 8];
    #pragma unroll
    for (int m = 0; m < 2; ++m)
        #pragma unroll
        for (int n = 0; n < 4; ++n)
            acc[m][n] = __builtin_amdgcn_mfma_f32_16x16x32_bf16(a[m], bb[n], acc[m][n], 0, 0, 0);

    #pragma unroll
    for (int m = 0; m < 2; ++m) {
        int mt = wave * 2 + m;
        float4 bv = *(const float4*)&b[mt * 16 + l16 * 4];
        #pragma unroll
        for (int n = 0; n < 4; ++n) {
            int row = row0 + n * 16 + l15;
            if (row < N) {
                ushort4 u;
                u.x = f2bf(reluf(acc[m][n][0] + bv.x));
                u.y = f2bf(reluf(acc[m][n][1] + bv.y));
                u.z = f2bf(reluf(acc[m][n][2] + bv.z));
                u.w = f2bf(reluf(acc[m][n][3] + bv.w));
                *(ushort4*)&h[(size_t)row * HDIM + mt * 16 + l16 * 4] = u;
            }
        }
    }
}

// ======================= fused enc + combine ================================
// Per 64-row dst tile:
//  stage x_dst -> x_s; stage msg -> act[:,128:256]      (coalesced)
//  enc MFMA (x_s) -> act[:,0:128]   (LDS only, h_dst never hits HBM pre-GEMM)
//  GEMM1 (K=256, act) -> z1 -> act[:,0:128] (aliased)
//  GEMM2 (K=128, z)   -> hout
// LDS 38.4 KB -> 4 blocks/CU.
#define ACT_STRIDE 264   // 256 + 8 bf16 pad
__global__ __launch_bounds__(256) void fused_enc_combine_kernel(
    const float* __restrict__ x, const bf16t* __restrict__ WEPl,
    const float* __restrict__ be, const bf16t* __restrict__ msg,
    const bf16t* __restrict__ W1P, const float* __restrict__ b1,
    const bf16t* __restrict__ W2P, const float* __restrict__ b2,
    bf16t* __restrict__ hout, int N)
{
    __shared__ bf16t x_s[64 * 36];             //  4,608 B
    __shared__ bf16t act_s[64 * ACT_STRIDE];   // 33,792 B

    const int tid  = threadIdx.x;
    const int row0 = blockIdx.x * 64;
    const int wave = tid >> 6, lane = tid & 63;
    const int l15 = lane & 15, l16 = lane >> 4;

    // stage x tile (bf16) and msg tile
    #pragma unroll
    for (int i = 0; i < 2; ++i) {
        int f = tid + i * 256;               // float4 idx in 64x32 fp32
        int r = f >> 3, c4 = f & 7;
        int row = row0 + r; if (row >= N) row = N - 1;
        float4 v = *(const float4*)&x[(size_t)row * FIN + c4 * 4];
        ushort4 u;
        u.x = f2bf(v.x); u.y = f2bf(v.y); u.z = f2bf(v.z); u.w = f2bf(v.w);
        *(ushort4*)&x_s[r * 36 + c4 * 4] = u;
    }
    #pragma unroll
    for (int i = 0; i < 4; ++i) {
        int f = tid + i * 256;               // 16B seg idx in 64x(128 bf16)
        int r = f >> 4, seg = f & 15;
        int row = row0 + r; if (row >= N) row = N - 1;
        *(float4*)&act_s[r * ACT_STRIDE + 128 + seg * 8] =
            *(const float4*)&msg[(size_t)row * HDIM + seg * 8];
    }
    __syncthreads();

    // inline encoder: relu(x@We+be) -> act[:,0:128]
    {
        f32x4 eacc[2][4];
        #pragma unroll
        for (int m = 0; m < 2; ++m)
            #pragma unroll
            for (int n = 0; n < 4; ++n)
                #pragma unroll
                for (int i = 0; i < 4; ++i) eacc[m][n][i] = 0.f;

        bf16x8 a[2], bb[4];
        #pragma unroll
        for (int m = 0; m < 2; ++m)
            a[m] = *(const bf16x8*)&WEPl[(((wave * 2 + m)) * 64 + lane) * 8];
        #pragma unroll
        for (int n = 0; n < 4; ++n)
            bb[n] = *(const bf16x8*)&x_s[(n * 16 + l15) * 36 + l16 * 8];
        #pragma unroll
        for (int m = 0; m < 2; ++m)
            #pragma unroll
            for (int n = 0; n < 4; ++n)
                eacc[m][n] = __builtin_amdgcn_mfma_f32_16x16x32_bf16(a[m], bb[n], eacc[m][n], 0, 0, 0);

        #pragma unroll
        for (int m = 0; m < 2; ++m) {
            int mt = wave * 2 + m;
            float4 bv = *(const float4*)&be[mt * 16 + l16 * 4];
            #pragma unroll
            for (int n = 0; n < 4; ++n) {
                int rl = n * 16 + l15;
                ushort4 u;
                u.x = f2bf(reluf(eacc[m][n][0] + bv.x));
                u.y = f2bf(reluf(eacc[m][n][1] + bv.y));
                u.z = f2bf(reluf(eacc[m][n][2] + bv.z));
                u.w = f2bf(reluf(eacc[m][n][3] + bv.w));
                *(ushort4*)&act_s[rl * ACT_STRIDE + mt * 16 + l16 * 4] = u;
            }
        }
    }
    __syncthreads();

    // GEMM1: K=256
    f32x4 acc1[2][4];
    #pragma unroll
    for (int m = 0; m < 2; ++m)
        #pragma unroll
        for (int n = 0; n < 4; ++n)
            #pragma unroll
            for (int i = 0; i < 4; ++i) acc1[m][n][i] = 0.f;

    for (int kc = 0; kc < 8; ++kc) {
        bf16x8 a[2], b[4];
        #pragma unroll
        for (int m = 0; m < 2; ++m) {
            int mt = wave * 2 + m;
            a[m] = *(const bf16x8*)&W1P[((kc * 8 + mt) * 64 + lane) * 8];
        }
        #pragma unroll
        for (int n = 0; n < 4; ++n)
            b[n] = *(const bf16x8*)&act_s[(n * 16 + l15) * ACT_STRIDE + kc * 32 + l16 * 8];
        #pragma unroll
        for (int m = 0; m < 2; ++m)
            #pragma unroll
            for (int n = 0; n < 4; ++n)
                acc1[m][n] = __builtin_amdgcn_mfma_f32_16x16x32_bf16(a[m], b[n], acc1[m][n], 0, 0, 0);
    }
    __syncthreads();   // all GEMM1 reads done before z overwrites act[:,0:128]

    // z1 = relu(acc1 + b1) -> act[:,0:128] (aliased)
    #pragma unroll
    for (int m = 0; m < 2; ++m) {
        int mt = wave * 2 + m;
        float4 bb = *(const float4*)&b1[mt * 16 + l16 * 4];
        #pragma unroll
        for (int n = 0; n < 4; ++n) {
            int zrow = n * 16 + l15;
            ushort4 u;
            u.x = f2bf(reluf(acc1[m][n][0] + bb.x));
            u.y = f2bf(reluf(acc1[m][n][1] + bb.y));
            u.z = f2bf(reluf(acc1[m][n][2] + bb.z));
            u.w = f2bf(reluf(acc1[m][n][3] + bb.w));
            *(ushort4*)&act_s[zrow * ACT_STRIDE + mt * 16 + l16 * 4] = u;
        }
    }
    __syncthreads();

    // GEMM2: K=128
    f32x4 acc2[2][4];
    #pragma unroll
    for (int m = 0; m < 2; ++m)
        #pragma unroll
        for (int n = 0; n < 4; ++n)
            #pragma unroll
            for (int i = 0; i < 4; ++i) acc2[m][n][i] = 0.f;

    for (int kc = 0; kc < 4; ++kc) {
        bf16x8 a[2], b[4];
        #pragma unroll
        for (int m = 0; m < 2; ++m) {
            int mt = wave * 2 + m;
            a[m] = *(const bf16x8*)&W2P[((kc * 8 + mt) * 64 + lane) * 8];
        }
        #pragma unroll
        for (int n = 0; n < 4; ++n)
            b[n] = *(const bf16x8*)&act_s[(n * 16 + l15) * ACT_STRIDE + kc * 32 + l16 * 8];
        #pragma unroll
        for (int m = 0; m < 2; ++m)
            #pragma unroll
            for (int n = 0; n < 4; ++n)
                acc2[m][n] = __builtin_amdgcn_mfma_f32_16x16x32_bf16(a[m], b[n], acc2[m][n], 0, 0, 0);
    }

    #pragma unroll
    for (int m = 0; m < 2; ++m) {
        int mt = wave * 2 + m;
        float4 bb = *(const float4*)&b2[mt * 16 + l16 * 4];
        #pragma unroll
        for (int n = 0; n < 4; ++n) {
            int row = row0 + n * 16 + l15;
            if (row < N) {
                ushort4 u;
                u.x = f2bf(reluf(acc2[m][n][0] + bb.x));
                u.y = f2bf(reluf(acc2[m][n][1] + bb.y));
                u.z = f2bf(reluf(acc2[m][n][2] + bb.z));
                u.w = f2bf(reluf(acc2[m][n][3] + bb.w));
                *(ushort4*)&hout[(size_t)row * HDIM + mt * 16 + l16 * 4] = u;
            }
        }
    }
}

// ======================= fused final MLP + rowdot ===========================
__global__ __launch_bounds__(256) void finale_kernel(
    const bf16t* __restrict__ he, const bf16t* __restrict__ W1P,
    const float* __restrict__ b1, const float* __restrict__ w2,
    const float* __restrict__ b2, float* __restrict__ out, int N)
{
    __shared__ float o_s[64];

    const int tid  = threadIdx.x;
    const int row0 = blockIdx.x * 64;
    const int wave = tid >> 6, lane = tid & 63;
    const int l15 = lane & 15, l16 = lane >> 4;

    if (tid < 64) o_s[tid] = 0.f;
    __syncthreads();

    int brow[4];
    #pragma unroll
    for (int n = 0; n < 4; ++n) {
        int r = row0 + n * 16 + l15;
        brow[n] = (r < N) ? r : (N - 1);
    }

    f32x4 acc[2][4];
    #pragma unroll
    for (int m = 0; m < 2; ++m)
        #pragma unroll
        for (int n = 0; n < 4; ++n)
            #pragma unroll
            for (int i = 0; i < 4; ++i) acc[m][n][i] = 0.f;

    #pragma unroll
    for (int kc = 0; kc < 4; ++kc) {
        const int koff = kc * 32 + l16 * 8;
        bf16x8 a[2], b[4];
        #pragma unroll
        for (int m = 0; m < 2; ++m) {
            int mt = wave * 2 + m;
            a[m] = *(const bf16x8*)&W1P[((kc * 8 + mt) * 64 + lane) * 8];
        }
        #pragma unroll
        for (int n = 0; n < 4; ++n)
            b[n] = *(const bf16x8*)&he[(size_t)brow[n] * HDIM + koff];
        #pragma unroll
        for (int m = 0; m < 2; ++m)
            #pragma unroll
            for (int n = 0; n < 4; ++n)
                acc[m][n] = __builtin_amdgcn_mfma_f32_16x16x32_bf16(a[m], b[n], acc[m][n], 0, 0, 0);
    }

    float s[4] = {0.f, 0.f, 0.f, 0.f};
    #pragma unroll
    for (int m = 0; m < 2; ++m) {
        int mt = wave * 2 + m;
        float4 bb = *(const float4*)&b1[mt * 16 + l16 * 4];
        float4 ww = *(const float4*)&w2[mt * 16 + l16 * 4];
        #pragma unroll
        for (int n = 0; n < 4; ++n) {
            s[n] += reluf(acc[m][n][0] + bb.x) * ww.x
                  + reluf(acc[m][n][1] + bb.y) * ww.y
                  + reluf(acc[m][n][2] + bb.z) * ww.z
                  + reluf(acc[m][n][3] + bb.w) * ww.w;
        }
    }
    #pragma unroll
    for (int n = 0; n < 4; ++n) {
        s[n] += __shfl_xor(s[n], 16, 64);
        s[n] += __shfl_xor(s[n], 32, 64);
        if (l16 == 0) atomicAdd(&o_s[n * 16 + l15], s[n]);
    }
    __syncthreads();
    if (tid < 64) {
        int row = row0 + tid;
        if (row < N) out[row] = o_s[tid] + b2[0];
    }
}

__global__ __launch_bounds__(256) void sentinel_kernel(float* out, int n, float val)
{
    int i = blockIdx.x * 256 + threadIdx.x;
    if (i < n) out[i] = (i == 0) ? val : 0.f;
}

// ---------------------------------------------------------------------------
static void build_csr(const int* src, const int* dst, int E, int N,
                      int* deg, int* start, int* cursor, int* eidx, int* bsum,
                      hipStream_t stream)
{
    const dim3 blk(256);
    hipMemsetAsync(deg, 0, (size_t)N * sizeof(int), stream);
    hist_kernel<<<dim3((E + 255) / 256), blk, 0, stream>>>(dst, deg, E);
    int B = (N + 1023) / 1024;
    scan_blocks_kernel<<<dim3(B), blk, 0, stream>>>(deg, start, bsum, N);
    scan_top_kernel<<<dim3(1), blk, 0, stream>>>(bsum, B);
    scan_add_kernel<<<dim3((N + 255) / 256), blk, 0, stream>>>(start, cursor, bsum, N);
    fill_kernel<<<dim3((E + 255) / 256), blk, 0, stream>>>(src, dst, cursor, eidx, E);
}

extern "C" void kernel_launch(void* const* d_in, const int* in_sizes, int n_in,
                              void* d_out, int out_size, void* d_ws, size_t ws_size,
                              hipStream_t stream)
{
    const float* x_col  = (const float*)d_in[0];
    const float* x_filt = (const float*)d_in[1];
    const float* x_pred = (const float*)d_in[2];
    const float* x_scan = (const float*)d_in[3];
    const float* x_join = (const float*)d_in[4];
    const float* x_enc  = (const float*)d_in[5];
    const float* W_enc  = (const float*)d_in[6];
    const float* b_enc  = (const float*)d_in[7];
    const float* W1t    = (const float*)d_in[8];
    const float* b1t    = (const float*)d_in[9];
    const float* W2t    = (const float*)d_in[10];
    const float* b2t    = (const float*)d_in[11];
    const float* Wf1    = (const float*)d_in[12];
    const float* bf1    = (const float*)d_in[13];
    const float* Wf2    = (const float*)d_in[14];
    const float* bf2    = (const float*)d_in[15];
    const int* src_cf = (const int*)d_in[16];
    const int* dst_cf = (const int*)d_in[17];
    const int* src_fp = (const int*)d_in[18];
    const int* dst_fp = (const int*)d_in[19];
    const int* src_ps = (const int*)d_in[20];
    const int* dst_ps = (const int*)d_in[21];
    const int* src_sj = (const int*)d_in[22];
    const int* dst_sj = (const int*)d_in[23];
    const int* src_je = (const int*)d_in[24];
    const int* dst_je = (const int*)d_in[25];

    const int N_COL  = in_sizes[0] / FIN;
    const int N_FILT = in_sizes[1] / FIN;
    const int N_PRED = in_sizes[2] / FIN;
    const int N_SCAN = in_sizes[3] / FIN;
    const int N_JOIN = in_sizes[4] / FIN;
    const int N_ENC  = in_sizes[5] / FIN;
    const int E_CF = in_sizes[16];
    const int E_FP = in_sizes[18];
    const int E_PS = in_sizes[20];
    const int E_SJ = in_sizes[22];
    const int E_JE = in_sizes[24];

    // ---- workspace layout (round-5 proven aliasing) ----
    size_t Mf = 0;
    {
        size_t c;
        c = (size_t)N_FILT * HDIM; if (c > Mf) Mf = c;
        c = (size_t)N_PRED * HDIM; if (c > Mf) Mf = c;
        c = (size_t)N_SCAN * HDIM; if (c > Mf) Mf = c;
        c = (size_t)N_JOIN * HDIM; if (c > Mf) Mf = c;
        c = (size_t)N_ENC  * HDIM; if (c > Mf) Mf = c;
    }
    size_t Hf = (size_t)N_COL * HDIM;
    { size_t c = (size_t)(N_FILT + N_PRED) * HDIM; if (c > Hf) Hf = c; }
    { size_t c = (size_t)(N_SCAN + N_JOIN + N_ENC + N_PRED) * HDIM; if (c > Hf) Hf = c; }

    int maxN = N_FILT;
    if (N_PRED > maxN) maxN = N_PRED;
    if (N_SCAN > maxN) maxN = N_SCAN;
    if (N_JOIN > maxN) maxN = N_JOIN;
    if (N_ENC  > maxN) maxN = N_ENC;
    int maxE = E_CF;
    if (E_FP > maxE) maxE = E_FP;
    if (E_PS > maxE) maxE = E_PS;
    if (E_SJ > maxE) maxE = E_SJ;
    if (E_JE > maxE) maxE = E_JE;

    const int W1P_TOT = 5 * 2 * HDIM * HDIM;   // 163840 bf16
    const int W2P_TOT = 5 * HDIM * HDIM;       //  81920 bf16
    const int WEP_TOT = 6 * FIN * HDIM;        //  24576 bf16
    const int WFP_TOT = HDIM * HDIM;           //  16384 bf16

    size_t msgB  = ((Mf * 2) + 255) & ~(size_t)255;
    size_t hB    = ((Hf * 2) + 255) & ~(size_t)255;
    size_t intB  = (((size_t)maxN * 4) + 255) & ~(size_t)255;
    size_t eidxB = (((size_t)maxE * 4) + 255) & ~(size_t)255;
    size_t wpB   = (((size_t)(W1P_TOT + W2P_TOT + WEP_TOT + WFP_TOT) * 2) + 255) & ~(size_t)255;
    size_t need  = msgB + hB + 3 * intB + eidxB + wpB + 8192;

    if (!d_ws || ws_size < need) {
        float val = 1.0e6f + (float)(ws_size >> 20);
        sentinel_kernel<<<dim3((out_size + 255) / 256), dim3(256), 0, stream>>>(
            (float*)d_out, out_size, val);
        return;
    }

    char* base = (char*)d_ws;
    bf16t* msg  = (bf16t*)base;                       base += msgB;
    bf16t* H    = (bf16t*)base;                       base += hB;
    int* deg    = (int*)base;                         base += intB;
    int* start  = (int*)base;                         base += intB;
    int* cursor = (int*)base;                         base += intB;
    int* eidx   = (int*)base;                         base += eidxB;
    bf16t* W1P  = (bf16t*)base;                       base += (size_t)W1P_TOT * 2;
    bf16t* W2P  = (bf16t*)base;                       base += (size_t)W2P_TOT * 2;
    bf16t* WEP  = (bf16t*)base;                       base += (size_t)WEP_TOT * 2;
    bf16t* WFP  = (bf16t*)base;                       base += (size_t)WFP_TOT * 2;
    int* bsum   = (int*)(((size_t)base + 255) & ~(size_t)255);

    bf16t* h_col  = H;                                 // dead after gather0
    bf16t* h_filt = H;                                 // overwritten by fused L0
    bf16t* h_pred = H + (size_t)N_FILT * HDIM;
    bf16t* h_scan = H;                                 // h_filt dead by then
    bf16t* h_join = H + (size_t)N_SCAN * HDIM;
    bf16t* h_enc  = H + (size_t)(N_SCAN + N_JOIN) * HDIM;

    const dim3 blk(256);

    // ---- weight repacks ----
    pack_w1_kernel<<<dim3((W1P_TOT + 255) / 256), blk, 0, stream>>>(W1t, W1P, W1P_TOT);
    pack_w2_kernel<<<dim3((W2P_TOT + 255) / 256), blk, 0, stream>>>(W2t, W2P, W2P_TOT);
    pack_we_kernel<<<dim3((WEP_TOT + 255) / 256), blk, 0, stream>>>(W_enc, WEP, WEP_TOT);
    pack_w2_kernel<<<dim3((WFP_TOT + 255) / 256), blk, 0, stream>>>(Wf1, WFP, WFP_TOT);

    // ---- level 0: column -> filter ----
    build_csr(src_cf, dst_cf, E_CF, N_FILT, deg, start, cursor, eidx, bsum, stream);
    enc_mfma_kernel<<<dim3((N_COL + 63) / 64), blk, 0, stream>>>(
        x_col, WEP, b_enc, h_col, N_COL);
    gather_kernel<<<dim3((N_FILT + 7) / 8), blk, 0, stream>>>(
        h_col, eidx, start, deg, msg, N_FILT);
    fused_enc_combine_kernel<<<dim3((N_FILT + 63) / 64), blk, 0, stream>>>(
        x_filt, WEP + 1 * FIN * HDIM, b_enc + 1 * HDIM, msg,
        W1P, b1t, W2P, b2t, h_filt, N_FILT);

    // ---- level 1: filter -> pred ----
    build_csr(src_fp, dst_fp, E_FP, N_PRED, deg, start, cursor, eidx, bsum, stream);
    gather_kernel<<<dim3((N_PRED + 7) / 8), blk, 0, stream>>>(
        h_filt, eidx, start, deg, msg, N_PRED);
    fused_enc_combine_kernel<<<dim3((N_PRED + 63) / 64), blk, 0, stream>>>(
        x_pred, WEP + 2 * FIN * HDIM, b_enc + 2 * HDIM, msg,
        W1P + 1 * 2 * HDIM * HDIM, b1t + 1 * HDIM,
        W2P + 1 * HDIM * HDIM, b2t + 1 * HDIM, h_pred, N_PRED);

    // ---- level 2: pred -> scan ----
    build_csr(src_ps, dst_ps, E_PS, N_SCAN, deg, start, cursor, eidx, bsum, stream);
    gather_kernel<<<dim3((N_SCAN + 7) / 8), blk, 0, stream>>>(
        h_pred, eidx, start, deg, msg, N_SCAN);
    fused_enc_combine_kernel<<<dim3((N_SCAN + 63) / 64), blk, 0, stream>>>(
        x_scan, WEP + 3 * FIN * HDIM, b_enc + 3 * HDIM, msg,
        W1P + 2 * 2 * HDIM * HDIM, b1t + 2 * HDIM,
        W2P + 2 * HDIM * HDIM, b2t + 2 * HDIM, h_scan, N_SCAN);

    // ---- level 3: scan -> join ----
    build_csr(src_sj, dst_sj, E_SJ, N_JOIN, deg, start, cursor, eidx, bsum, stream);
    gather_kernel<<<dim3((N_JOIN + 7) / 8), blk, 0, stream>>>(
        h_scan, eidx, start, deg, msg, N_JOIN);
    fused_enc_combine_kernel<<<dim3((N_JOIN + 63) / 64), blk, 0, stream>>>(
        x_join, WEP + 4 * FIN * HDIM, b_enc + 4 * HDIM, msg,
        W1P + 3 * 2 * HDIM * HDIM, b1t + 3 * HDIM,
        W2P + 3 * HDIM * HDIM, b2t + 3 * HDIM, h_join, N_JOIN);

    // ---- level 4: join -> encode ----
    build_csr(src_je, dst_je, E_JE, N_ENC, deg, start, cursor, eidx, bsum, stream);
    gather_kernel<<<dim3((N_ENC + 7) / 8), blk, 0, stream>>>(
        h_join, eidx, start, deg, msg, N_ENC);
    fused_enc_combine_kernel<<<dim3((N_ENC + 63) / 64), blk, 0, stream>>>(
        x_enc, WEP + 5 * FIN * HDIM, b_enc + 5 * HDIM, msg,
        W1P + 4 * 2 * HDIM * HDIM, b1t + 4 * HDIM,
        W2P + 4 * HDIM * HDIM, b2t + 4 * HDIM, h_enc, N_ENC);

    // ---- fused final MLP + projection ----
    finale_kernel<<<dim3((N_ENC + 63) / 64), blk, 0, stream>>>(
        h_enc, WFP, bf1, Wf2, bf2, (float*)d_out, N_ENC);
}

// Round 9
// 456.778 us; speedup vs baseline: 1.4011x; 1.0971x over previous
//
#include <hip/hip_runtime.h>
#include <hip/hip_bf16.h>

#define HDIM 128
#define FIN  32

typedef __hip_bfloat16 bf16t;
using bf16x8 = __attribute__((ext_vector_type(8))) short;
using f32x4  = __attribute__((ext_vector_type(4))) float;

__device__ __forceinline__ float reluf(float x) { return x > 0.f ? x : 0.f; }

__device__ __forceinline__ unsigned short f2bf(float f) {
    unsigned int b = __float_as_uint(f);
    b += 0x7FFFu + ((b >> 16) & 1u);       // round-to-nearest-even
    return (unsigned short)(b >> 16);
}
__device__ __forceinline__ float bf2f(unsigned short u) {
    return __uint_as_float(((unsigned int)u) << 16);
}

__device__ __forceinline__ float4 ld4(const bf16t* p) {
    ushort4 u = *(const ushort4*)p;
    return make_float4(bf2f(u.x), bf2f(u.y), bf2f(u.z), bf2f(u.w));
}
__device__ __forceinline__ void st4(bf16t* p, float4 v) {
    ushort4 u;
    u.x = f2bf(v.x); u.y = f2bf(v.y); u.z = f2bf(v.z); u.w = f2bf(v.w);
    *(ushort4*)p = u;
}

// ======================= consolidated CSR construction ======================
// All 5 levels built in one pass over concatenated node/edge index spaces.
__global__ __launch_bounds__(256) void hist_all_kernel(
    const int* __restrict__ d0, const int* __restrict__ d1,
    const int* __restrict__ d2, const int* __restrict__ d3,
    const int* __restrict__ d4,
    int c1, int c2, int c3, int c4, int ET,     // cumulative edge ends 1..4
    int n0, int n1, int n2, int n3, int n4,     // node offsets
    int* __restrict__ deg)
{
    int i = blockIdx.x * 256 + threadIdx.x;
    if (i >= ET) return;
    int d, off;
    if      (i < c1) { d = d0[i];      off = n0; }
    else if (i < c2) { d = d1[i - c1]; off = n1; }
    else if (i < c3) { d = d2[i - c2]; off = n2; }
    else if (i < c4) { d = d3[i - c3]; off = n3; }
    else             { d = d4[i - c4]; off = n4; }
    atomicAdd(&deg[off + d], 1);
}

__global__ __launch_bounds__(256) void fill_all_kernel(
    const int* __restrict__ s0, const int* __restrict__ s1,
    const int* __restrict__ s2, const int* __restrict__ s3,
    const int* __restrict__ s4,
    const int* __restrict__ d0, const int* __restrict__ d1,
    const int* __restrict__ d2, const int* __restrict__ d3,
    const int* __restrict__ d4,
    int c1, int c2, int c3, int c4, int ET,
    int n0, int n1, int n2, int n3, int n4,
    int* __restrict__ cursor, int* __restrict__ eidx)
{
    int i = blockIdx.x * 256 + threadIdx.x;
    if (i >= ET) return;
    int s, d, off;
    if      (i < c1) { s = s0[i];      d = d0[i];      off = n0; }
    else if (i < c2) { s = s1[i - c1]; d = d1[i - c1]; off = n1; }
    else if (i < c3) { s = s2[i - c2]; d = d2[i - c2]; off = n2; }
    else if (i < c4) { s = s3[i - c3]; d = d3[i - c3]; off = n3; }
    else             { s = s4[i - c4]; d = d4[i - c4]; off = n4; }
    int p = atomicAdd(&cursor[off + d], 1);
    eidx[p] = s;
}

// per-1024-chunk exclusive scan; bsum[chunk] = chunk total
__global__ __launch_bounds__(256) void scan_blocks_kernel(
    const int* __restrict__ deg, int* __restrict__ start,
    int* __restrict__ bsum, int N)
{
    __shared__ int s[256];
    const int t = threadIdx.x;
    const int base = blockIdx.x * 1024;
    int v[4], tsum = 0;
    #pragma unroll
    for (int i = 0; i < 4; ++i) {
        int idx = base + t * 4 + i;
        v[i] = (idx < N) ? deg[idx] : 0;
        tsum += v[i];
    }
    s[t] = tsum; __syncthreads();
    for (int off = 1; off < 256; off <<= 1) {
        int x = (t >= off) ? s[t - off] : 0;
        __syncthreads();
        s[t] += x;
        __syncthreads();
    }
    if (t == 255) bsum[blockIdx.x] = s[255];
    int run = s[t] - tsum;
    #pragma unroll
    for (int i = 0; i < 4; ++i) {
        int idx = base + t * 4 + i;
        if (idx < N) start[idx] = run;
        run += v[i];
    }
}

// single-block exclusive scan of bsum[B], B <= 1024
__global__ __launch_bounds__(256) void scan_top_kernel(int* __restrict__ bsum, int B)
{
    __shared__ int s[256];
    const int t = threadIdx.x;
    int v[4], tsum = 0;
    #pragma unroll
    for (int i = 0; i < 4; ++i) {
        int idx = t * 4 + i;
        v[i] = (idx < B) ? bsum[idx] : 0;
        tsum += v[i];
    }
    s[t] = tsum; __syncthreads();
    for (int off = 1; off < 256; off <<= 1) {
        int x = (t >= off) ? s[t - off] : 0;
        __syncthreads();
        s[t] += x;
        __syncthreads();
    }
    int run = s[t] - tsum;
    #pragma unroll
    for (int i = 0; i < 4; ++i) {
        int idx = t * 4 + i;
        if (idx < B) bsum[idx] = run;
        run += v[i];
    }
}

__global__ __launch_bounds__(256) void scan_add_kernel(
    int* __restrict__ start, int* __restrict__ cursor,
    const int* __restrict__ bsum, int N)
{
    int i = blockIdx.x * 256 + threadIdx.x;
    if (i < N) {
        int v = start[i] + bsum[i >> 10];
        start[i]  = v;
        cursor[i] = v;
    }
}

// ======================= gather-based segment sum ===========================
__global__ __launch_bounds__(256) void gather_kernel(
    const bf16t* __restrict__ h, const int* __restrict__ eidx,
    const int* __restrict__ start, const int* __restrict__ deg,
    bf16t* __restrict__ msg, int N)
{
    int r = blockIdx.x * 8 + (threadIdx.x >> 5);
    if (r >= N) return;
    int lane = threadIdx.x & 31;
    int s0 = start[r], cnt = deg[r];
    float4 acc = make_float4(0.f, 0.f, 0.f, 0.f);
    for (int j = s0; j < s0 + cnt; ++j) {
        int s = eidx[j];
        float4 v = ld4(&h[(size_t)s * HDIM + lane * 4]);
        acc.x += v.x; acc.y += v.y; acc.z += v.z; acc.w += v.w;
    }
    st4(&msg[(size_t)r * HDIM + lane * 4], acc);
}

// ======================= weight repack (MFMA A-fragment order) ==============
__global__ __launch_bounds__(256) void pack_w1_kernel(
    const float* __restrict__ W1t, bf16t* __restrict__ W1P, int total)
{
    int q = blockIdx.x * 256 + threadIdx.x;
    if (q >= total) return;
    int L = q >> 15;                 // 32768 per level (K=256, 8 kc x 8 mt)
    int r = q & 32767;
    int j = r & 7, l = (r >> 3) & 63, mt = (r >> 9) & 7, kc = (r >> 12) & 7;
    float v = W1t[(size_t)L * 2 * HDIM * HDIM +
                  (size_t)(kc * 32 + ((l >> 4) & 3) * 8 + j) * HDIM + mt * 16 + (l & 15)];
    *(unsigned short*)&W1P[q] = f2bf(v);
}

__global__ __launch_bounds__(256) void pack_w2_kernel(
    const float* __restrict__ W2t, bf16t* __restrict__ W2P, int total)
{
    int q = blockIdx.x * 256 + threadIdx.x;
    if (q >= total) return;
    int L = q >> 14;                 // 16384 per level (K=128, 4 kc x 8 mt)
    int r = q & 16383;
    int j = r & 7, l = (r >> 3) & 63, mt = (r >> 9) & 7, kc = (r >> 12) & 3;
    float v = W2t[(size_t)L * HDIM * HDIM +
                  (size_t)(kc * 32 + ((l >> 4) & 3) * 8 + j) * HDIM + mt * 16 + (l & 15)];
    *(unsigned short*)&W2P[q] = f2bf(v);
}

__global__ __launch_bounds__(256) void pack_we_kernel(
    const float* __restrict__ We, bf16t* __restrict__ WeP, int total)
{
    int q = blockIdx.x * 256 + threadIdx.x;
    if (q >= total) return;
    int enc = q >> 12;
    int r = q & 4095;
    int j = r & 7, l = (r >> 3) & 63, mt = (r >> 9) & 7;
    int k = ((l >> 4) & 3) * 8 + j;
    float v = We[(size_t)enc * FIN * HDIM + (size_t)k * HDIM + mt * 16 + (l & 15)];
    *(unsigned short*)&WeP[q] = f2bf(v);
}

// ======================= MFMA encoder (h_col only) ==========================
__global__ __launch_bounds__(256) void enc_mfma_kernel(
    const float* __restrict__ x, const bf16t* __restrict__ WP,
    const float* __restrict__ b, bf16t* __restrict__ h, int N)
{
    __shared__ bf16t x_s[64 * 36];
    const int tid  = threadIdx.x;
    const int row0 = blockIdx.x * 64;
    const int wave = tid >> 6, lane = tid & 63;
    const int l15 = lane & 15, l16 = lane >> 4;

    #pragma unroll
    for (int i = 0; i < 2; ++i) {
        int f = tid + i * 256;
        int r = f >> 3, c4 = f & 7;
        int row = row0 + r; if (row >= N) row = N - 1;
        float4 v = *(const float4*)&x[(size_t)row * FIN + c4 * 4];
        ushort4 u;
        u.x = f2bf(v.x); u.y = f2bf(v.y); u.z = f2bf(v.z); u.w = f2bf(v.w);
        *(ushort4*)&x_s[r * 36 + c4 * 4] = u;
    }
    __syncthreads();

    f32x4 acc[2][4];
    #pragma unroll
    for (int m = 0; m < 2; ++m)
        #pragma unroll
        for (int n = 0; n < 4; ++n)
            #pragma unroll
            for (int i = 0; i < 4; ++i) acc[m][n][i] = 0.f;

    bf16x8 a[2], bb[4];
    #pragma unroll
    for (int m = 0; m < 2; ++m)
        a[m] = *(const bf16x8*)&WP[(((wave * 2 + m)) * 64 + lane) * 8];
    #pragma unroll
    for (int n = 0; n < 4; ++n)
        bb[n] = *(const bf16x8*)&x_s[(n * 16 + l15) * 36 + l16 * 8];
    #pragma unroll
    for (int m = 0; m < 2; ++m)
        #pragma unroll
        for (int n = 0; n < 4; ++n)
            acc[m][n] = __builtin_amdgcn_mfma_f32_16x16x32_bf16(a[m], bb[n], acc[m][n], 0, 0, 0);

    #pragma unroll
    for (int m = 0; m < 2; ++m) {
        int mt = wave * 2 + m;
        float4 bv = *(const float4*)&b[mt * 16 + l16 * 4];
        #pragma unroll
        for (int n = 0; n < 4; ++n) {
            int row = row0 + n * 16 + l15;
            if (row < N) {
                ushort4 u;
                u.x = f2bf(reluf(acc[m][n][0] + bv.x));
                u.y = f2bf(reluf(acc[m][n][1] + bv.y));
                u.z = f2bf(reluf(acc[m][n][2] + bv.z));
                u.w = f2bf(reluf(acc[m][n][3] + bv.w));
                *(ushort4*)&h[(size_t)row * HDIM + mt * 16 + l16 * 4] = u;
            }
        }
    }
}

// ======================= fused enc + combine (round-8 proven) ===============
#define ACT_STRIDE 264   // 256 + 8 bf16 pad
__global__ __launch_bounds__(256) void fused_enc_combine_kernel(
    const float* __restrict__ x, const bf16t* __restrict__ WEPl,
    const float* __restrict__ be, const bf16t* __restrict__ msg,
    const bf16t* __restrict__ W1P, const float* __restrict__ b1,
    const bf16t* __restrict__ W2P, const float* __restrict__ b2,
    bf16t* __restrict__ hout, int N)
{
    __shared__ bf16t x_s[64 * 36];             //  4,608 B
    __shared__ bf16t act_s[64 * ACT_STRIDE];   // 33,792 B

    const int tid  = threadIdx.x;
    const int row0 = blockIdx.x * 64;
    const int wave = tid >> 6, lane = tid & 63;
    const int l15 = lane & 15, l16 = lane >> 4;

    #pragma unroll
    for (int i = 0; i < 2; ++i) {
        int f = tid + i * 256;
        int r = f >> 3, c4 = f & 7;
        int row = row0 + r; if (row >= N) row = N - 1;
        float4 v = *(const float4*)&x[(size_t)row * FIN + c4 * 4];
        ushort4 u;
        u.x = f2bf(v.x); u.y = f2bf(v.y); u.z = f2bf(v.z); u.w = f2bf(v.w);
        *(ushort4*)&x_s[r * 36 + c4 * 4] = u;
    }
    #pragma unroll
    for (int i = 0; i < 4; ++i) {
        int f = tid + i * 256;
        int r = f >> 4, seg = f & 15;
        int row = row0 + r; if (row >= N) row = N - 1;
        *(float4*)&act_s[r * ACT_STRIDE + 128 + seg * 8] =
            *(const float4*)&msg[(size_t)row * HDIM + seg * 8];
    }
    __syncthreads();

    {
        f32x4 eacc[2][4];
        #pragma unroll
        for (int m = 0; m < 2; ++m)
            #pragma unroll
            for (int n = 0; n < 4; ++n)
                #pragma unroll
                for (int i = 0; i < 4; ++i) eacc[m][n][i] = 0.f;

        bf16x8 a[2], bb[4];
        #pragma unroll
        for (int m = 0; m < 2; ++m)
            a[m] = *(const bf16x8*)&WEPl[(((wave * 2 + m)) * 64 + lane) * 8];
        #pragma unroll
        for (int n = 0; n < 4; ++n)
            bb[n] = *(const bf16x8*)&x_s[(n * 16 + l15) * 36 + l16 * 8];
        #pragma unroll
        for (int m = 0; m < 2; ++m)
            #pragma unroll
            for (int n = 0; n < 4; ++n)
                eacc[m][n] = __builtin_amdgcn_mfma_f32_16x16x32_bf16(a[m], bb[n], eacc[m][n], 0, 0, 0);

        #pragma unroll
        for (int m = 0; m < 2; ++m) {
            int mt = wave * 2 + m;
            float4 bv = *(const float4*)&be[mt * 16 + l16 * 4];
            #pragma unroll
            for (int n = 0; n < 4; ++n) {
                int rl = n * 16 + l15;
                ushort4 u;
                u.x = f2bf(reluf(eacc[m][n][0] + bv.x));
                u.y = f2bf(reluf(eacc[m][n][1] + bv.y));
                u.z = f2bf(reluf(eacc[m][n][2] + bv.z));
                u.w = f2bf(reluf(eacc[m][n][3] + bv.w));
                *(ushort4*)&act_s[rl * ACT_STRIDE + mt * 16 + l16 * 4] = u;
            }
        }
    }
    __syncthreads();

    f32x4 acc1[2][4];
    #pragma unroll
    for (int m = 0; m < 2; ++m)
        #pragma unroll
        for (int n = 0; n < 4; ++n)
            #pragma unroll
            for (int i = 0; i < 4; ++i) acc1[m][n][i] = 0.f;

    for (int kc = 0; kc < 8; ++kc) {
        bf16x8 a[2], b[4];
        #pragma unroll
        for (int m = 0; m < 2; ++m) {
            int mt = wave * 2 + m;
            a[m] = *(const bf16x8*)&W1P[((kc * 8 + mt) * 64 + lane) * 8];
        }
        #pragma unroll
        for (int n = 0; n < 4; ++n)
            b[n] = *(const bf16x8*)&act_s[(n * 16 + l15) * ACT_STRIDE + kc * 32 + l16 * 8];
        #pragma unroll
        for (int m = 0; m < 2; ++m)
            #pragma unroll
            for (int n = 0; n < 4; ++n)
                acc1[m][n] = __builtin_amdgcn_mfma_f32_16x16x32_bf16(a[m], b[n], acc1[m][n], 0, 0, 0);
    }
    __syncthreads();

    #pragma unroll
    for (int m = 0; m < 2; ++m) {
        int mt = wave * 2 + m;
        float4 bb = *(const float4*)&b1[mt * 16 + l16 * 4];
        #pragma unroll
        for (int n = 0; n < 4; ++n) {
            int zrow = n * 16 + l15;
            ushort4 u;
            u.x = f2bf(reluf(acc1[m][n][0] + bb.x));
            u.y = f2bf(reluf(acc1[m][n][1] + bb.y));
            u.z = f2bf(reluf(acc1[m][n][2] + bb.z));
            u.w = f2bf(reluf(acc1[m][n][3] + bb.w));
            *(ushort4*)&act_s[zrow * ACT_STRIDE + mt * 16 + l16 * 4] = u;
        }
    }
    __syncthreads();

    f32x4 acc2[2][4];
    #pragma unroll
    for (int m = 0; m < 2; ++m)
        #pragma unroll
        for (int n = 0; n < 4; ++n)
            #pragma unroll
            for (int i = 0; i < 4; ++i) acc2[m][n][i] = 0.f;

    for (int kc = 0; kc < 4; ++kc) {
        bf16x8 a[2], b[4];
        #pragma unroll
        for (int m = 0; m < 2; ++m) {
            int mt = wave * 2 + m;
            a[m] = *(const bf16x8*)&W2P[((kc * 8 + mt) * 64 + lane) * 8];
        }
        #pragma unroll
        for (int n = 0; n < 4; ++n)
            b[n] = *(const bf16x8*)&act_s[(n * 16 + l15) * ACT_STRIDE + kc * 32 + l16 * 8];
        #pragma unroll
        for (int m = 0; m < 2; ++m)
            #pragma unroll
            for (int n = 0; n < 4; ++n)
                acc2[m][n] = __builtin_amdgcn_mfma_f32_16x16x32_bf16(a[m], b[n], acc2[m][n], 0, 0, 0);
    }

    #pragma unroll
    for (int m = 0; m < 2; ++m) {
        int mt = wave * 2 + m;
        float4 bb = *(const float4*)&b2[mt * 16 + l16 * 4];
        #pragma unroll
        for (int n = 0; n < 4; ++n) {
            int row = row0 + n * 16 + l15;
            if (row < N) {
                ushort4 u;
                u.x = f2bf(reluf(acc2[m][n][0] + bb.x));
                u.y = f2bf(reluf(acc2[m][n][1] + bb.y));
                u.z = f2bf(reluf(acc2[m][n][2] + bb.z));
                u.w = f2bf(reluf(acc2[m][n][3] + bb.w));
                *(ushort4*)&hout[(size_t)row * HDIM + mt * 16 + l16 * 4] = u;
            }
        }
    }
}

// ======================= fused final MLP + rowdot ===========================
__global__ __launch_bounds__(256) void finale_kernel(
    const bf16t* __restrict__ he, const bf16t* __restrict__ W1P,
    const float* __restrict__ b1, const float* __restrict__ w2,
    const float* __restrict__ b2, float* __restrict__ out, int N)
{
    __shared__ float o_s[64];

    const int tid  = threadIdx.x;
    const int row0 = blockIdx.x * 64;
    const int wave = tid >> 6, lane = tid & 63;
    const int l15 = lane & 15, l16 = lane >> 4;

    if (tid < 64) o_s[tid] = 0.f;
    __syncthreads();

    int brow[4];
    #pragma unroll
    for (int n = 0; n < 4; ++n) {
        int r = row0 + n * 16 + l15;
        brow[n] = (r < N) ? r : (N - 1);
    }

    f32x4 acc[2][4];
    #pragma unroll
    for (int m = 0; m < 2; ++m)
        #pragma unroll
        for (int n = 0; n < 4; ++n)
            #pragma unroll
            for (int i = 0; i < 4; ++i) acc[m][n][i] = 0.f;

    #pragma unroll
    for (int kc = 0; kc < 4; ++kc) {
        const int koff = kc * 32 + l16 * 8;
        bf16x8 a[2], b[4];
        #pragma unroll
        for (int m = 0; m < 2; ++m) {
            int mt = wave * 2 + m;
            a[m] = *(const bf16x8*)&W1P[((kc * 8 + mt) * 64 + lane) * 8];
        }
        #pragma unroll
        for (int n = 0; n < 4; ++n)
            b[n] = *(const bf16x8*)&he[(size_t)brow[n] * HDIM + koff];
        #pragma unroll
        for (int m = 0; m < 2; ++m)
            #pragma unroll
            for (int n = 0; n < 4; ++n)
                acc[m][n] = __builtin_amdgcn_mfma_f32_16x16x32_bf16(a[m], b[n], acc[m][n], 0, 0, 0);
    }

    float s[4] = {0.f, 0.f, 0.f, 0.f};
    #pragma unroll
    for (int m = 0; m < 2; ++m) {
        int mt = wave * 2 + m;
        float4 bb = *(const float4*)&b1[mt * 16 + l16 * 4];
        float4 ww = *(const float4*)&w2[mt * 16 + l16 * 4];
        #pragma unroll
        for (int n = 0; n < 4; ++n) {
            s[n] += reluf(acc[m][n][0] + bb.x) * ww.x
                  + reluf(acc[m][n][1] + bb.y) * ww.y
                  + reluf(acc[m][n][2] + bb.z) * ww.z
                  + reluf(acc[m][n][3] + bb.w) * ww.w;
        }
    }
    #pragma unroll
    for (int n = 0; n < 4; ++n) {
        s[n] += __shfl_xor(s[n], 16, 64);
        s[n] += __shfl_xor(s[n], 32, 64);
        if (l16 == 0) atomicAdd(&o_s[n * 16 + l15], s[n]);
    }
    __syncthreads();
    if (tid < 64) {
        int row = row0 + tid;
        if (row < N) out[row] = o_s[tid] + b2[0];
    }
}

__global__ __launch_bounds__(256) void sentinel_kernel(float* out, int n, float val)
{
    int i = blockIdx.x * 256 + threadIdx.x;
    if (i < n) out[i] = (i == 0) ? val : 0.f;
}

extern "C" void kernel_launch(void* const* d_in, const int* in_sizes, int n_in,
                              void* d_out, int out_size, void* d_ws, size_t ws_size,
                              hipStream_t stream)
{
    const float* x_col  = (const float*)d_in[0];
    const float* x_filt = (const float*)d_in[1];
    const float* x_pred = (const float*)d_in[2];
    const float* x_scan = (const float*)d_in[3];
    const float* x_join = (const float*)d_in[4];
    const float* x_enc  = (const float*)d_in[5];
    const float* W_enc  = (const float*)d_in[6];
    const float* b_enc  = (const float*)d_in[7];
    const float* W1t    = (const float*)d_in[8];
    const float* b1t    = (const float*)d_in[9];
    const float* W2t    = (const float*)d_in[10];
    const float* b2t    = (const float*)d_in[11];
    const float* Wf1    = (const float*)d_in[12];
    const float* bf1    = (const float*)d_in[13];
    const float* Wf2    = (const float*)d_in[14];
    const float* bf2    = (const float*)d_in[15];
    const int* src_cf = (const int*)d_in[16];
    const int* dst_cf = (const int*)d_in[17];
    const int* src_fp = (const int*)d_in[18];
    const int* dst_fp = (const int*)d_in[19];
    const int* src_ps = (const int*)d_in[20];
    const int* dst_ps = (const int*)d_in[21];
    const int* src_sj = (const int*)d_in[22];
    const int* dst_sj = (const int*)d_in[23];
    const int* src_je = (const int*)d_in[24];
    const int* dst_je = (const int*)d_in[25];

    const int N_COL  = in_sizes[0] / FIN;
    const int N_FILT = in_sizes[1] / FIN;
    const int N_PRED = in_sizes[2] / FIN;
    const int N_SCAN = in_sizes[3] / FIN;
    const int N_JOIN = in_sizes[4] / FIN;
    const int N_ENC  = in_sizes[5] / FIN;
    const int E_CF = in_sizes[16];
    const int E_FP = in_sizes[18];
    const int E_PS = in_sizes[20];
    const int E_SJ = in_sizes[22];
    const int E_JE = in_sizes[24];

    // concatenated node / edge spaces
    const int n0 = 0;
    const int n1 = n0 + N_FILT;
    const int n2 = n1 + N_PRED;
    const int n3 = n2 + N_SCAN;
    const int n4 = n3 + N_JOIN;
    const int NT = n4 + N_ENC;
    const int c1 = E_CF;
    const int c2 = c1 + E_FP;
    const int c3 = c2 + E_PS;
    const int c4 = c3 + E_SJ;
    const int ET = c4 + E_JE;

    // ---- workspace layout ----
    size_t Mf = 0;
    {
        size_t c;
        c = (size_t)N_FILT * HDIM; if (c > Mf) Mf = c;
        c = (size_t)N_PRED * HDIM; if (c > Mf) Mf = c;
        c = (size_t)N_SCAN * HDIM; if (c > Mf) Mf = c;
        c = (size_t)N_JOIN * HDIM; if (c > Mf) Mf = c;
        c = (size_t)N_ENC  * HDIM; if (c > Mf) Mf = c;
    }
    size_t Hf = (size_t)N_COL * HDIM;
    { size_t c = (size_t)(N_FILT + N_PRED) * HDIM; if (c > Hf) Hf = c; }
    { size_t c = (size_t)(N_SCAN + N_JOIN + N_ENC + N_PRED) * HDIM; if (c > Hf) Hf = c; }

    const int W1P_TOT = 5 * 2 * HDIM * HDIM;   // 163840 bf16
    const int W2P_TOT = 5 * HDIM * HDIM;       //  81920 bf16
    const int WEP_TOT = 6 * FIN * HDIM;        //  24576 bf16
    const int WFP_TOT = HDIM * HDIM;           //  16384 bf16

    size_t msgB  = ((Mf * 2) + 255) & ~(size_t)255;
    size_t hB    = ((Hf * 2) + 255) & ~(size_t)255;
    size_t intB  = (((size_t)NT * 4) + 255) & ~(size_t)255;
    size_t eidxB = (((size_t)ET * 4) + 255) & ~(size_t)255;
    size_t wpB   = (((size_t)(W1P_TOT + W2P_TOT + WEP_TOT + WFP_TOT) * 2) + 255) & ~(size_t)255;
    size_t need  = msgB + hB + 3 * intB + eidxB + wpB + 8192;

    if (!d_ws || ws_size < need) {
        float val = 1.0e6f + (float)(ws_size >> 20);
        sentinel_kernel<<<dim3((out_size + 255) / 256), dim3(256), 0, stream>>>(
            (float*)d_out, out_size, val);
        return;
    }

    char* base = (char*)d_ws;
    bf16t* msg  = (bf16t*)base;                       base += msgB;
    bf16t* H    = (bf16t*)base;                       base += hB;
    int* deg    = (int*)base;                         base += intB;
    int* start  = (int*)base;                         base += intB;
    int* cursor = (int*)base;                         base += intB;
    int* eidx   = (int*)base;                         base += eidxB;
    bf16t* W1P  = (bf16t*)base;                       base += (size_t)W1P_TOT * 2;
    bf16t* W2P  = (bf16t*)base;                       base += (size_t)W2P_TOT * 2;
    bf16t* WEP  = (bf16t*)base;                       base += (size_t)WEP_TOT * 2;
    bf16t* WFP  = (bf16t*)base;                       base += (size_t)WFP_TOT * 2;
    int* bsum   = (int*)(((size_t)base + 255) & ~(size_t)255);

    bf16t* h_col  = H;                                 // dead after gather0
    bf16t* h_filt = H;                                 // overwritten by fused L0
    bf16t* h_pred = H + (size_t)N_FILT * HDIM;
    bf16t* h_scan = H;                                 // h_filt dead by then
    bf16t* h_join = H + (size_t)N_SCAN * HDIM;
    bf16t* h_enc  = H + (size_t)(N_SCAN + N_JOIN) * HDIM;

    const dim3 blk(256);

    // ---- consolidated CSR build (all 5 levels, one pass) ----
    hipMemsetAsync(deg, 0, (size_t)NT * sizeof(int), stream);
    hist_all_kernel<<<dim3((ET + 255) / 256), blk, 0, stream>>>(
        dst_cf, dst_fp, dst_ps, dst_sj, dst_je,
        c1, c2, c3, c4, ET, n0, n1, n2, n3, n4, deg);
    int B = (NT + 1023) / 1024;
    scan_blocks_kernel<<<dim3(B), blk, 0, stream>>>(deg, start, bsum, NT);
    scan_top_kernel<<<dim3(1), blk, 0, stream>>>(bsum, B);
    scan_add_kernel<<<dim3((NT + 255) / 256), blk, 0, stream>>>(start, cursor, bsum, NT);
    fill_all_kernel<<<dim3((ET + 255) / 256), blk, 0, stream>>>(
        src_cf, src_fp, src_ps, src_sj, src_je,
        dst_cf, dst_fp, dst_ps, dst_sj, dst_je,
        c1, c2, c3, c4, ET, n0, n1, n2, n3, n4, cursor, eidx);

    // ---- weight repacks ----
    pack_w1_kernel<<<dim3((W1P_TOT + 255) / 256), blk, 0, stream>>>(W1t, W1P, W1P_TOT);
    pack_w2_kernel<<<dim3((W2P_TOT + 255) / 256), blk, 0, stream>>>(W2t, W2P, W2P_TOT);
    pack_we_kernel<<<dim3((WEP_TOT + 255) / 256), blk, 0, stream>>>(W_enc, WEP, WEP_TOT);
    pack_w2_kernel<<<dim3((WFP_TOT + 255) / 256), blk, 0, stream>>>(Wf1, WFP, WFP_TOT);

    // ---- h_col encoder ----
    enc_mfma_kernel<<<dim3((N_COL + 63) / 64), blk, 0, stream>>>(
        x_col, WEP, b_enc, h_col, N_COL);

    // ---- level 0: column -> filter ----
    gather_kernel<<<dim3((N_FILT + 7) / 8), blk, 0, stream>>>(
        h_col, eidx, start + n0, deg + n0, msg, N_FILT);
    fused_enc_combine_kernel<<<dim3((N_FILT + 63) / 64), blk, 0, stream>>>(
        x_filt, WEP + 1 * FIN * HDIM, b_enc + 1 * HDIM, msg,
        W1P, b1t, W2P, b2t, h_filt, N_FILT);

    // ---- level 1: filter -> pred ----
    gather_kernel<<<dim3((N_PRED + 7) / 8), blk, 0, stream>>>(
        h_filt, eidx, start + n1, deg + n1, msg, N_PRED);
    fused_enc_combine_kernel<<<dim3((N_PRED + 63) / 64), blk, 0, stream>>>(
        x_pred, WEP + 2 * FIN * HDIM, b_enc + 2 * HDIM, msg,
        W1P + 1 * 2 * HDIM * HDIM, b1t + 1 * HDIM,
        W2P + 1 * HDIM * HDIM, b2t + 1 * HDIM, h_pred, N_PRED);

    // ---- level 2: pred -> scan ----
    gather_kernel<<<dim3((N_SCAN + 7) / 8), blk, 0, stream>>>(
        h_pred, eidx, start + n2, deg + n2, msg, N_SCAN);
    fused_enc_combine_kernel<<<dim3((N_SCAN + 63) / 64), blk, 0, stream>>>(
        x_scan, WEP + 3 * FIN * HDIM, b_enc + 3 * HDIM, msg,
        W1P + 2 * 2 * HDIM * HDIM, b1t + 2 * HDIM,
        W2P + 2 * HDIM * HDIM, b2t + 2 * HDIM, h_scan, N_SCAN);

    // ---- level 3: scan -> join ----
    gather_kernel<<<dim3((N_JOIN + 7) / 8), blk, 0, stream>>>(
        h_scan, eidx, start + n3, deg + n3, msg, N_JOIN);
    fused_enc_combine_kernel<<<dim3((N_JOIN + 63) / 64), blk, 0, stream>>>(
        x_join, WEP + 4 * FIN * HDIM, b_enc + 4 * HDIM, msg,
        W1P + 3 * 2 * HDIM * HDIM, b1t + 3 * HDIM,
        W2P + 3 * HDIM * HDIM, b2t + 3 * HDIM, h_join, N_JOIN);

    // ---- level 4: join -> encode ----
    gather_kernel<<<dim3((N_ENC + 7) / 8), blk, 0, stream>>>(
        h_join, eidx, start + n4, deg + n4, msg, N_ENC);
    fused_enc_combine_kernel<<<dim3((N_ENC + 63) / 64), blk, 0, stream>>>(
        x_enc, WEP + 5 * FIN * HDIM, b_enc + 5 * HDIM, msg,
        W1P + 4 * 2 * HDIM * HDIM, b1t + 4 * HDIM,
        W2P + 4 * HDIM * HDIM, b2t + 4 * HDIM, h_enc, N_ENC);

    // ---- fused final MLP + projection ----
    finale_kernel<<<dim3((N_ENC + 63) / 64), blk, 0, stream>>>(
        h_enc, WFP, bf1, Wf2, bf2, (float*)d_out, N_ENC);
}

// Round 10
// 415.587 us; speedup vs baseline: 1.5399x; 1.0991x over previous
//
#include <hip/hip_runtime.h>
#include <hip/hip_bf16.h>

#define HDIM 128
#define FIN  32

typedef __hip_bfloat16 bf16t;
using bf16x8 = __attribute__((ext_vector_type(8))) short;
using f32x4  = __attribute__((ext_vector_type(4))) float;

__device__ __forceinline__ float reluf(float x) { return x > 0.f ? x : 0.f; }

__device__ __forceinline__ unsigned short f2bf(float f) {
    unsigned int b = __float_as_uint(f);
    b += 0x7FFFu + ((b >> 16) & 1u);       // round-to-nearest-even
    return (unsigned short)(b >> 16);
}
__device__ __forceinline__ float bf2f(unsigned short u) {
    return __uint_as_float(((unsigned int)u) << 16);
}

__device__ __forceinline__ float4 ld4(const bf16t* p) {
    ushort4 u = *(const ushort4*)p;
    return make_float4(bf2f(u.x), bf2f(u.y), bf2f(u.z), bf2f(u.w));
}
__device__ __forceinline__ void st4(bf16t* p, float4 v) {
    ushort4 u;
    u.x = f2bf(v.x); u.y = f2bf(v.y); u.z = f2bf(v.z); u.w = f2bf(v.w);
    *(ushort4*)p = u;
}

// ======================= consolidated CSR construction ======================
// hist also emits each edge's intra-row rank (the atomicAdd return value),
// making the fill pass atomic-free.
__global__ __launch_bounds__(256) void hist_all_kernel(
    const int* __restrict__ d0, const int* __restrict__ d1,
    const int* __restrict__ d2, const int* __restrict__ d3,
    const int* __restrict__ d4,
    int c1, int c2, int c3, int c4, int ET,     // cumulative edge ends 1..4
    int n0, int n1, int n2, int n3, int n4,     // node offsets
    int* __restrict__ deg, int* __restrict__ rank)
{
    int i = blockIdx.x * 256 + threadIdx.x;
    if (i >= ET) return;
    int d, off;
    if      (i < c1) { d = d0[i];      off = n0; }
    else if (i < c2) { d = d1[i - c1]; off = n1; }
    else if (i < c3) { d = d2[i - c2]; off = n2; }
    else if (i < c4) { d = d3[i - c3]; off = n3; }
    else             { d = d4[i - c4]; off = n4; }
    rank[i] = atomicAdd(&deg[off + d], 1);
}

__global__ __launch_bounds__(256) void fill_all_kernel(
    const int* __restrict__ s0, const int* __restrict__ s1,
    const int* __restrict__ s2, const int* __restrict__ s3,
    const int* __restrict__ s4,
    const int* __restrict__ d0, const int* __restrict__ d1,
    const int* __restrict__ d2, const int* __restrict__ d3,
    const int* __restrict__ d4,
    int c1, int c2, int c3, int c4, int ET,
    int n0, int n1, int n2, int n3, int n4,
    const int* __restrict__ start, const int* __restrict__ rank,
    int* __restrict__ eidx)
{
    int i = blockIdx.x * 256 + threadIdx.x;
    if (i >= ET) return;
    int s, d, off;
    if      (i < c1) { s = s0[i];      d = d0[i];      off = n0; }
    else if (i < c2) { s = s1[i - c1]; d = d1[i - c1]; off = n1; }
    else if (i < c3) { s = s2[i - c2]; d = d2[i - c2]; off = n2; }
    else if (i < c4) { s = s3[i - c3]; d = d3[i - c3]; off = n3; }
    else             { s = s4[i - c4]; d = d4[i - c4]; off = n4; }
    eidx[start[off + d] + rank[i]] = s;
}

// per-1024-chunk exclusive scan; bsum[chunk] = chunk total
__global__ __launch_bounds__(256) void scan_blocks_kernel(
    const int* __restrict__ deg, int* __restrict__ start,
    int* __restrict__ bsum, int N)
{
    __shared__ int s[256];
    const int t = threadIdx.x;
    const int base = blockIdx.x * 1024;
    int v[4], tsum = 0;
    #pragma unroll
    for (int i = 0; i < 4; ++i) {
        int idx = base + t * 4 + i;
        v[i] = (idx < N) ? deg[idx] : 0;
        tsum += v[i];
    }
    s[t] = tsum; __syncthreads();
    for (int off = 1; off < 256; off <<= 1) {
        int x = (t >= off) ? s[t - off] : 0;
        __syncthreads();
        s[t] += x;
        __syncthreads();
    }
    if (t == 255) bsum[blockIdx.x] = s[255];
    int run = s[t] - tsum;
    #pragma unroll
    for (int i = 0; i < 4; ++i) {
        int idx = base + t * 4 + i;
        if (idx < N) start[idx] = run;
        run += v[i];
    }
}

// single-block exclusive scan of bsum[B], B <= 1024
__global__ __launch_bounds__(256) void scan_top_kernel(int* __restrict__ bsum, int B)
{
    __shared__ int s[256];
    const int t = threadIdx.x;
    int v[4], tsum = 0;
    #pragma unroll
    for (int i = 0; i < 4; ++i) {
        int idx = t * 4 + i;
        v[i] = (idx < B) ? bsum[idx] : 0;
        tsum += v[i];
    }
    s[t] = tsum; __syncthreads();
    for (int off = 1; off < 256; off <<= 1) {
        int x = (t >= off) ? s[t - off] : 0;
        __syncthreads();
        s[t] += x;
        __syncthreads();
    }
    int run = s[t] - tsum;
    #pragma unroll
    for (int i = 0; i < 4; ++i) {
        int idx = t * 4 + i;
        if (idx < B) bsum[idx] = run;
        run += v[i];
    }
}

__global__ __launch_bounds__(256) void scan_add_kernel(
    int* __restrict__ start, const int* __restrict__ bsum, int N)
{
    int i = blockIdx.x * 256 + threadIdx.x;
    if (i < N) start[i] += bsum[i >> 10];
}

// ======================= gather-based segment sum ===========================
__global__ __launch_bounds__(256) void gather_kernel(
    const bf16t* __restrict__ h, const int* __restrict__ eidx,
    const int* __restrict__ start, const int* __restrict__ deg,
    bf16t* __restrict__ msg, int N)
{
    int r = blockIdx.x * 8 + (threadIdx.x >> 5);
    if (r >= N) return;
    int lane = threadIdx.x & 31;
    int s0 = start[r], cnt = deg[r];
    float4 acc = make_float4(0.f, 0.f, 0.f, 0.f);
    for (int j = s0; j < s0 + cnt; ++j) {
        int s = eidx[j];
        float4 v = ld4(&h[(size_t)s * HDIM + lane * 4]);
        acc.x += v.x; acc.y += v.y; acc.z += v.z; acc.w += v.w;
    }
    st4(&msg[(size_t)r * HDIM + lane * 4], acc);
}

// ======================= weight repack (MFMA A-fragment order) ==============
__global__ __launch_bounds__(256) void pack_w1_kernel(
    const float* __restrict__ W1t, bf16t* __restrict__ W1P, int total)
{
    int q = blockIdx.x * 256 + threadIdx.x;
    if (q >= total) return;
    int L = q >> 15;                 // 32768 per level (K=256, 8 kc x 8 mt)
    int r = q & 32767;
    int j = r & 7, l = (r >> 3) & 63, mt = (r >> 9) & 7, kc = (r >> 12) & 7;
    float v = W1t[(size_t)L * 2 * HDIM * HDIM +
                  (size_t)(kc * 32 + ((l >> 4) & 3) * 8 + j) * HDIM + mt * 16 + (l & 15)];
    *(unsigned short*)&W1P[q] = f2bf(v);
}

__global__ __launch_bounds__(256) void pack_w2_kernel(
    const float* __restrict__ W2t, bf16t* __restrict__ W2P, int total)
{
    int q = blockIdx.x * 256 + threadIdx.x;
    if (q >= total) return;
    int L = q >> 14;                 // 16384 per level (K=128, 4 kc x 8 mt)
    int r = q & 16383;
    int j = r & 7, l = (r >> 3) & 63, mt = (r >> 9) & 7, kc = (r >> 12) & 3;
    float v = W2t[(size_t)L * HDIM * HDIM +
                  (size_t)(kc * 32 + ((l >> 4) & 3) * 8 + j) * HDIM + mt * 16 + (l & 15)];
    *(unsigned short*)&W2P[q] = f2bf(v);
}

__global__ __launch_bounds__(256) void pack_we_kernel(
    const float* __restrict__ We, bf16t* __restrict__ WeP, int total)
{
    int q = blockIdx.x * 256 + threadIdx.x;
    if (q >= total) return;
    int enc = q >> 12;
    int r = q & 4095;
    int j = r & 7, l = (r >> 3) & 63, mt = (r >> 9) & 7;
    int k = ((l >> 4) & 3) * 8 + j;
    float v = We[(size_t)enc * FIN * HDIM + (size_t)k * HDIM + mt * 16 + (l & 15)];
    *(unsigned short*)&WeP[q] = f2bf(v);
}

// ======================= MFMA encoder (h_col only) ==========================
__global__ __launch_bounds__(256) void enc_mfma_kernel(
    const float* __restrict__ x, const bf16t* __restrict__ WP,
    const float* __restrict__ b, bf16t* __restrict__ h, int N)
{
    __shared__ bf16t x_s[64 * 36];
    const int tid  = threadIdx.x;
    const int row0 = blockIdx.x * 64;
    const int wave = tid >> 6, lane = tid & 63;
    const int l15 = lane & 15, l16 = lane >> 4;

    #pragma unroll
    for (int i = 0; i < 2; ++i) {
        int f = tid + i * 256;
        int r = f >> 3, c4 = f & 7;
        int row = row0 + r; if (row >= N) row = N - 1;
        float4 v = *(const float4*)&x[(size_t)row * FIN + c4 * 4];
        ushort4 u;
        u.x = f2bf(v.x); u.y = f2bf(v.y); u.z = f2bf(v.z); u.w = f2bf(v.w);
        *(ushort4*)&x_s[r * 36 + c4 * 4] = u;
    }
    __syncthreads();

    f32x4 acc[2][4];
    #pragma unroll
    for (int m = 0; m < 2; ++m)
        #pragma unroll
        for (int n = 0; n < 4; ++n)
            #pragma unroll
            for (int i = 0; i < 4; ++i) acc[m][n][i] = 0.f;

    bf16x8 a[2], bb[4];
    #pragma unroll
    for (int m = 0; m < 2; ++m)
        a[m] = *(const bf16x8*)&WP[(((wave * 2 + m)) * 64 + lane) * 8];
    #pragma unroll
    for (int n = 0; n < 4; ++n)
        bb[n] = *(const bf16x8*)&x_s[(n * 16 + l15) * 36 + l16 * 8];
    #pragma unroll
    for (int m = 0; m < 2; ++m)
        #pragma unroll
        for (int n = 0; n < 4; ++n)
            acc[m][n] = __builtin_amdgcn_mfma_f32_16x16x32_bf16(a[m], bb[n], acc[m][n], 0, 0, 0);

    #pragma unroll
    for (int m = 0; m < 2; ++m) {
        int mt = wave * 2 + m;
        float4 bv = *(const float4*)&b[mt * 16 + l16 * 4];
        #pragma unroll
        for (int n = 0; n < 4; ++n) {
            int row = row0 + n * 16 + l15;
            if (row < N) {
                ushort4 u;
                u.x = f2bf(reluf(acc[m][n][0] + bv.x));
                u.y = f2bf(reluf(acc[m][n][1] + bv.y));
                u.z = f2bf(reluf(acc[m][n][2] + bv.z));
                u.w = f2bf(reluf(acc[m][n][3] + bv.w));
                *(ushort4*)&h[(size_t)row * HDIM + mt * 16 + l16 * 4] = u;
            }
        }
    }
}

// ======================= fused enc + combine (round-8 proven) ===============
#define ACT_STRIDE 264   // 256 + 8 bf16 pad
__global__ __launch_bounds__(256) void fused_enc_combine_kernel(
    const float* __restrict__ x, const bf16t* __restrict__ WEPl,
    const float* __restrict__ be, const bf16t* __restrict__ msg,
    const bf16t* __restrict__ W1P, const float* __restrict__ b1,
    const bf16t* __restrict__ W2P, const float* __restrict__ b2,
    bf16t* __restrict__ hout, int N)
{
    __shared__ bf16t x_s[64 * 36];             //  4,608 B
    __shared__ bf16t act_s[64 * ACT_STRIDE];   // 33,792 B

    const int tid  = threadIdx.x;
    const int row0 = blockIdx.x * 64;
    const int wave = tid >> 6, lane = tid & 63;
    const int l15 = lane & 15, l16 = lane >> 4;

    #pragma unroll
    for (int i = 0; i < 2; ++i) {
        int f = tid + i * 256;
        int r = f >> 3, c4 = f & 7;
        int row = row0 + r; if (row >= N) row = N - 1;
        float4 v = *(const float4*)&x[(size_t)row * FIN + c4 * 4];
        ushort4 u;
        u.x = f2bf(v.x); u.y = f2bf(v.y); u.z = f2bf(v.z); u.w = f2bf(v.w);
        *(ushort4*)&x_s[r * 36 + c4 * 4] = u;
    }
    #pragma unroll
    for (int i = 0; i < 4; ++i) {
        int f = tid + i * 256;
        int r = f >> 4, seg = f & 15;
        int row = row0 + r; if (row >= N) row = N - 1;
        *(float4*)&act_s[r * ACT_STRIDE + 128 + seg * 8] =
            *(const float4*)&msg[(size_t)row * HDIM + seg * 8];
    }
    __syncthreads();

    {
        f32x4 eacc[2][4];
        #pragma unroll
        for (int m = 0; m < 2; ++m)
            #pragma unroll
            for (int n = 0; n < 4; ++n)
                #pragma unroll
                for (int i = 0; i < 4; ++i) eacc[m][n][i] = 0.f;

        bf16x8 a[2], bb[4];
        #pragma unroll
        for (int m = 0; m < 2; ++m)
            a[m] = *(const bf16x8*)&WEPl[(((wave * 2 + m)) * 64 + lane) * 8];
        #pragma unroll
        for (int n = 0; n < 4; ++n)
            bb[n] = *(const bf16x8*)&x_s[(n * 16 + l15) * 36 + l16 * 8];
        #pragma unroll
        for (int m = 0; m < 2; ++m)
            #pragma unroll
            for (int n = 0; n < 4; ++n)
                eacc[m][n] = __builtin_amdgcn_mfma_f32_16x16x32_bf16(a[m], bb[n], eacc[m][n], 0, 0, 0);

        #pragma unroll
        for (int m = 0; m < 2; ++m) {
            int mt = wave * 2 + m;
            float4 bv = *(const float4*)&be[mt * 16 + l16 * 4];
            #pragma unroll
            for (int n = 0; n < 4; ++n) {
                int rl = n * 16 + l15;
                ushort4 u;
                u.x = f2bf(reluf(eacc[m][n][0] + bv.x));
                u.y = f2bf(reluf(eacc[m][n][1] + bv.y));
                u.z = f2bf(reluf(eacc[m][n][2] + bv.z));
                u.w = f2bf(reluf(eacc[m][n][3] + bv.w));
                *(ushort4*)&act_s[rl * ACT_STRIDE + mt * 16 + l16 * 4] = u;
            }
        }
    }
    __syncthreads();

    f32x4 acc1[2][4];
    #pragma unroll
    for (int m = 0; m < 2; ++m)
        #pragma unroll
        for (int n = 0; n < 4; ++n)
            #pragma unroll
            for (int i = 0; i < 4; ++i) acc1[m][n][i] = 0.f;

    for (int kc = 0; kc < 8; ++kc) {
        bf16x8 a[2], b[4];
        #pragma unroll
        for (int m = 0; m < 2; ++m) {
            int mt = wave * 2 + m;
            a[m] = *(const bf16x8*)&W1P[((kc * 8 + mt) * 64 + lane) * 8];
        }
        #pragma unroll
        for (int n = 0; n < 4; ++n)
            b[n] = *(const bf16x8*)&act_s[(n * 16 + l15) * ACT_STRIDE + kc * 32 + l16 * 8];
        #pragma unroll
        for (int m = 0; m < 2; ++m)
            #pragma unroll
            for (int n = 0; n < 4; ++n)
                acc1[m][n] = __builtin_amdgcn_mfma_f32_16x16x32_bf16(a[m], b[n], acc1[m][n], 0, 0, 0);
    }
    __syncthreads();

    #pragma unroll
    for (int m = 0; m < 2; ++m) {
        int mt = wave * 2 + m;
        float4 bb = *(const float4*)&b1[mt * 16 + l16 * 4];
        #pragma unroll
        for (int n = 0; n < 4; ++n) {
            int zrow = n * 16 + l15;
            ushort4 u;
            u.x = f2bf(reluf(acc1[m][n][0] + bb.x));
            u.y = f2bf(reluf(acc1[m][n][1] + bb.y));
            u.z = f2bf(reluf(acc1[m][n][2] + bb.z));
            u.w = f2bf(reluf(acc1[m][n][3] + bb.w));
            *(ushort4*)&act_s[zrow * ACT_STRIDE + mt * 16 + l16 * 4] = u;
        }
    }
    __syncthreads();

    f32x4 acc2[2][4];
    #pragma unroll
    for (int m = 0; m < 2; ++m)
        #pragma unroll
        for (int n = 0; n < 4; ++n)
            #pragma unroll
            for (int i = 0; i < 4; ++i) acc2[m][n][i] = 0.f;

    for (int kc = 0; kc < 4; ++kc) {
        bf16x8 a[2], b[4];
        #pragma unroll
        for (int m = 0; m < 2; ++m) {
            int mt = wave * 2 + m;
            a[m] = *(const bf16x8*)&W2P[((kc * 8 + mt) * 64 + lane) * 8];
        }
        #pragma unroll
        for (int n = 0; n < 4; ++n)
            b[n] = *(const bf16x8*)&act_s[(n * 16 + l15) * ACT_STRIDE + kc * 32 + l16 * 8];
        #pragma unroll
        for (int m = 0; m < 2; ++m)
            #pragma unroll
            for (int n = 0; n < 4; ++n)
                acc2[m][n] = __builtin_amdgcn_mfma_f32_16x16x32_bf16(a[m], b[n], acc2[m][n], 0, 0, 0);
    }

    #pragma unroll
    for (int m = 0; m < 2; ++m) {
        int mt = wave * 2 + m;
        float4 bb = *(const float4*)&b2[mt * 16 + l16 * 4];
        #pragma unroll
        for (int n = 0; n < 4; ++n) {
            int row = row0 + n * 16 + l15;
            if (row < N) {
                ushort4 u;
                u.x = f2bf(reluf(acc2[m][n][0] + bb.x));
                u.y = f2bf(reluf(acc2[m][n][1] + bb.y));
                u.z = f2bf(reluf(acc2[m][n][2] + bb.z));
                u.w = f2bf(reluf(acc2[m][n][3] + bb.w));
                *(ushort4*)&hout[(size_t)row * HDIM + mt * 16 + l16 * 4] = u;
            }
        }
    }
}

// ======================= fused final MLP + rowdot ===========================
__global__ __launch_bounds__(256) void finale_kernel(
    const bf16t* __restrict__ he, const bf16t* __restrict__ W1P,
    const float* __restrict__ b1, const float* __restrict__ w2,
    const float* __restrict__ b2, float* __restrict__ out, int N)
{
    __shared__ float o_s[64];

    const int tid  = threadIdx.x;
    const int row0 = blockIdx.x * 64;
    const int wave = tid >> 6, lane = tid & 63;
    const int l15 = lane & 15, l16 = lane >> 4;

    if (tid < 64) o_s[tid] = 0.f;
    __syncthreads();

    int brow[4];
    #pragma unroll
    for (int n = 0; n < 4; ++n) {
        int r = row0 + n * 16 + l15;
        brow[n] = (r < N) ? r : (N - 1);
    }

    f32x4 acc[2][4];
    #pragma unroll
    for (int m = 0; m < 2; ++m)
        #pragma unroll
        for (int n = 0; n < 4; ++n)
            #pragma unroll
            for (int i = 0; i < 4; ++i) acc[m][n][i] = 0.f;

    #pragma unroll
    for (int kc = 0; kc < 4; ++kc) {
        const int koff = kc * 32 + l16 * 8;
        bf16x8 a[2], b[4];
        #pragma unroll
        for (int m = 0; m < 2; ++m) {
            int mt = wave * 2 + m;
            a[m] = *(const bf16x8*)&W1P[((kc * 8 + mt) * 64 + lane) * 8];
        }
        #pragma unroll
        for (int n = 0; n < 4; ++n)
            b[n] = *(const bf16x8*)&he[(size_t)brow[n] * HDIM + koff];
        #pragma unroll
        for (int m = 0; m < 2; ++m)
            #pragma unroll
            for (int n = 0; n < 4; ++n)
                acc[m][n] = __builtin_amdgcn_mfma_f32_16x16x32_bf16(a[m], b[n], acc[m][n], 0, 0, 0);
    }

    float s[4] = {0.f, 0.f, 0.f, 0.f};
    #pragma unroll
    for (int m = 0; m < 2; ++m) {
        int mt = wave * 2 + m;
        float4 bb = *(const float4*)&b1[mt * 16 + l16 * 4];
        float4 ww = *(const float4*)&w2[mt * 16 + l16 * 4];
        #pragma unroll
        for (int n = 0; n < 4; ++n) {
            s[n] += reluf(acc[m][n][0] + bb.x) * ww.x
                  + reluf(acc[m][n][1] + bb.y) * ww.y
                  + reluf(acc[m][n][2] + bb.z) * ww.z
                  + reluf(acc[m][n][3] + bb.w) * ww.w;
        }
    }
    #pragma unroll
    for (int n = 0; n < 4; ++n) {
        s[n] += __shfl_xor(s[n], 16, 64);
        s[n] += __shfl_xor(s[n], 32, 64);
        if (l16 == 0) atomicAdd(&o_s[n * 16 + l15], s[n]);
    }
    __syncthreads();
    if (tid < 64) {
        int row = row0 + tid;
        if (row < N) out[row] = o_s[tid] + b2[0];
    }
}

__global__ __launch_bounds__(256) void sentinel_kernel(float* out, int n, float val)
{
    int i = blockIdx.x * 256 + threadIdx.x;
    if (i < n) out[i] = (i == 0) ? val : 0.f;
}

extern "C" void kernel_launch(void* const* d_in, const int* in_sizes, int n_in,
                              void* d_out, int out_size, void* d_ws, size_t ws_size,
                              hipStream_t stream)
{
    const float* x_col  = (const float*)d_in[0];
    const float* x_filt = (const float*)d_in[1];
    const float* x_pred = (const float*)d_in[2];
    const float* x_scan = (const float*)d_in[3];
    const float* x_join = (const float*)d_in[4];
    const float* x_enc  = (const float*)d_in[5];
    const float* W_enc  = (const float*)d_in[6];
    const float* b_enc  = (const float*)d_in[7];
    const float* W1t    = (const float*)d_in[8];
    const float* b1t    = (const float*)d_in[9];
    const float* W2t    = (const float*)d_in[10];
    const float* b2t    = (const float*)d_in[11];
    const float* Wf1    = (const float*)d_in[12];
    const float* bf1    = (const float*)d_in[13];
    const float* Wf2    = (const float*)d_in[14];
    const float* bf2    = (const float*)d_in[15];
    const int* src_cf = (const int*)d_in[16];
    const int* dst_cf = (const int*)d_in[17];
    const int* src_fp = (const int*)d_in[18];
    const int* dst_fp = (const int*)d_in[19];
    const int* src_ps = (const int*)d_in[20];
    const int* dst_ps = (const int*)d_in[21];
    const int* src_sj = (const int*)d_in[22];
    const int* dst_sj = (const int*)d_in[23];
    const int* src_je = (const int*)d_in[24];
    const int* dst_je = (const int*)d_in[25];

    const int N_COL  = in_sizes[0] / FIN;
    const int N_FILT = in_sizes[1] / FIN;
    const int N_PRED = in_sizes[2] / FIN;
    const int N_SCAN = in_sizes[3] / FIN;
    const int N_JOIN = in_sizes[4] / FIN;
    const int N_ENC  = in_sizes[5] / FIN;
    const int E_CF = in_sizes[16];
    const int E_FP = in_sizes[18];
    const int E_PS = in_sizes[20];
    const int E_SJ = in_sizes[22];
    const int E_JE = in_sizes[24];

    // concatenated node / edge spaces
    const int n0 = 0;
    const int n1 = n0 + N_FILT;
    const int n2 = n1 + N_PRED;
    const int n3 = n2 + N_SCAN;
    const int n4 = n3 + N_JOIN;
    const int NT = n4 + N_ENC;
    const int c1 = E_CF;
    const int c2 = c1 + E_FP;
    const int c3 = c2 + E_PS;
    const int c4 = c3 + E_SJ;
    const int ET = c4 + E_JE;

    // ---- workspace layout ----
    size_t Mf = 0;
    {
        size_t c;
        c = (size_t)N_FILT * HDIM; if (c > Mf) Mf = c;
        c = (size_t)N_PRED * HDIM; if (c > Mf) Mf = c;
        c = (size_t)N_SCAN * HDIM; if (c > Mf) Mf = c;
        c = (size_t)N_JOIN * HDIM; if (c > Mf) Mf = c;
        c = (size_t)N_ENC  * HDIM; if (c > Mf) Mf = c;
    }
    size_t Hf = (size_t)N_COL * HDIM;
    { size_t c = (size_t)(N_FILT + N_PRED) * HDIM; if (c > Hf) Hf = c; }
    { size_t c = (size_t)(N_SCAN + N_JOIN + N_ENC + N_PRED) * HDIM; if (c > Hf) Hf = c; }

    const int W1P_TOT = 5 * 2 * HDIM * HDIM;   // 163840 bf16
    const int W2P_TOT = 5 * HDIM * HDIM;       //  81920 bf16
    const int WEP_TOT = 6 * FIN * HDIM;        //  24576 bf16
    const int WFP_TOT = HDIM * HDIM;           //  16384 bf16

    size_t msgB  = ((Mf * 2) + 255) & ~(size_t)255;
    size_t hB    = ((Hf * 2) + 255) & ~(size_t)255;
    size_t intB  = (((size_t)NT * 4) + 255) & ~(size_t)255;
    size_t eidxB = (((size_t)ET * 4) + 255) & ~(size_t)255;
    size_t wpB   = (((size_t)(W1P_TOT + W2P_TOT + WEP_TOT + WFP_TOT) * 2) + 255) & ~(size_t)255;
    size_t need  = msgB + hB + 2 * intB + 2 * eidxB + wpB + 8192;

    if (!d_ws || ws_size < need) {
        float val = 1.0e6f + (float)(ws_size >> 20);
        sentinel_kernel<<<dim3((out_size + 255) / 256), dim3(256), 0, stream>>>(
            (float*)d_out, out_size, val);
        return;
    }

    char* base = (char*)d_ws;
    bf16t* msg  = (bf16t*)base;                       base += msgB;
    bf16t* H    = (bf16t*)base;                       base += hB;
    int* deg    = (int*)base;                         base += intB;
    int* start  = (int*)base;                         base += intB;
    int* rank   = (int*)base;                         base += eidxB;
    int* eidx   = (int*)base;                         base += eidxB;
    bf16t* W1P  = (bf16t*)base;                       base += (size_t)W1P_TOT * 2;
    bf16t* W2P  = (bf16t*)base;                       base += (size_t)W2P_TOT * 2;
    bf16t* WEP  = (bf16t*)base;                       base += (size_t)WEP_TOT * 2;
    bf16t* WFP  = (bf16t*)base;                       base += (size_t)WFP_TOT * 2;
    int* bsum   = (int*)(((size_t)base + 255) & ~(size_t)255);

    bf16t* h_col  = H;                                 // dead after gather0
    bf16t* h_filt = H;                                 // overwritten by fused L0
    bf16t* h_pred = H + (size_t)N_FILT * HDIM;
    bf16t* h_scan = H;                                 // h_filt dead by then
    bf16t* h_join = H + (size_t)N_SCAN * HDIM;
    bf16t* h_enc  = H + (size_t)(N_SCAN + N_JOIN) * HDIM;

    const dim3 blk(256);

    // ---- consolidated CSR build (atomic-free fill) ----
    hipMemsetAsync(deg, 0, (size_t)NT * sizeof(int), stream);
    hist_all_kernel<<<dim3((ET + 255) / 256), blk, 0, stream>>>(
        dst_cf, dst_fp, dst_ps, dst_sj, dst_je,
        c1, c2, c3, c4, ET, n0, n1, n2, n3, n4, deg, rank);
    int B = (NT + 1023) / 1024;
    scan_blocks_kernel<<<dim3(B), blk, 0, stream>>>(deg, start, bsum, NT);
    scan_top_kernel<<<dim3(1), blk, 0, stream>>>(bsum, B);
    scan_add_kernel<<<dim3((NT + 255) / 256), blk, 0, stream>>>(start, bsum, NT);
    fill_all_kernel<<<dim3((ET + 255) / 256), blk, 0, stream>>>(
        src_cf, src_fp, src_ps, src_sj, src_je,
        dst_cf, dst_fp, dst_ps, dst_sj, dst_je,
        c1, c2, c3, c4, ET, n0, n1, n2, n3, n4, start, rank, eidx);

    // ---- weight repacks ----
    pack_w1_kernel<<<dim3((W1P_TOT + 255) / 256), blk, 0, stream>>>(W1t, W1P, W1P_TOT);
    pack_w2_kernel<<<dim3((W2P_TOT + 255) / 256), blk, 0, stream>>>(W2t, W2P, W2P_TOT);
    pack_we_kernel<<<dim3((WEP_TOT + 255) / 256), blk, 0, stream>>>(W_enc, WEP, WEP_TOT);
    pack_w2_kernel<<<dim3((WFP_TOT + 255) / 256), blk, 0, stream>>>(Wf1, WFP, WFP_TOT);

    // ---- h_col encoder ----
    enc_mfma_kernel<<<dim3((N_COL + 63) / 64), blk, 0, stream>>>(
        x_col, WEP, b_enc, h_col, N_COL);

    // ---- level 0: column -> filter ----
    gather_kernel<<<dim3((N_FILT + 7) / 8), blk, 0, stream>>>(
        h_col, eidx, start + n0, deg + n0, msg, N_FILT);
    fused_enc_combine_kernel<<<dim3((N_FILT + 63) / 64), blk, 0, stream>>>(
        x_filt, WEP + 1 * FIN * HDIM, b_enc + 1 * HDIM, msg,
        W1P, b1t, W2P, b2t, h_filt, N_FILT);

    // ---- level 1: filter -> pred ----
    gather_kernel<<<dim3((N_PRED + 7) / 8), blk, 0, stream>>>(
        h_filt, eidx, start + n1, deg + n1, msg, N_PRED);
    fused_enc_combine_kernel<<<dim3((N_PRED + 63) / 64), blk, 0, stream>>>(
        x_pred, WEP + 2 * FIN * HDIM, b_enc + 2 * HDIM, msg,
        W1P + 1 * 2 * HDIM * HDIM, b1t + 1 * HDIM,
        W2P + 1 * HDIM * HDIM, b2t + 1 * HDIM, h_pred, N_PRED);

    // ---- level 2: pred -> scan ----
    gather_kernel<<<dim3((N_SCAN + 7) / 8), blk, 0, stream>>>(
        h_pred, eidx, start + n2, deg + n2, msg, N_SCAN);
    fused_enc_combine_kernel<<<dim3((N_SCAN + 63) / 64), blk, 0, stream>>>(
        x_scan, WEP + 3 * FIN * HDIM, b_enc + 3 * HDIM, msg,
        W1P + 2 * 2 * HDIM * HDIM, b1t + 2 * HDIM,
        W2P + 2 * HDIM * HDIM, b2t + 2 * HDIM, h_scan, N_SCAN);

    // ---- level 3: scan -> join ----
    gather_kernel<<<dim3((N_JOIN + 7) / 8), blk, 0, stream>>>(
        h_scan, eidx, start + n3, deg + n3, msg, N_JOIN);
    fused_enc_combine_kernel<<<dim3((N_JOIN + 63) / 64), blk, 0, stream>>>(
        x_join, WEP + 4 * FIN * HDIM, b_enc + 4 * HDIM, msg,
        W1P + 3 * 2 * HDIM * HDIM, b1t + 3 * HDIM,
        W2P + 3 * HDIM * HDIM, b2t + 3 * HDIM, h_join, N_JOIN);

    // ---- level 4: join -> encode ----
    gather_kernel<<<dim3((N_ENC + 7) / 8), blk, 0, stream>>>(
        h_join, eidx, start + n4, deg + n4, msg, N_ENC);
    fused_enc_combine_kernel<<<dim3((N_ENC + 63) / 64), blk, 0, stream>>>(
        x_enc, WEP + 5 * FIN * HDIM, b_enc + 5 * HDIM, msg,
        W1P + 4 * 2 * HDIM * HDIM, b1t + 4 * HDIM,
        W2P + 4 * HDIM * HDIM, b2t + 4 * HDIM, h_enc, N_ENC);

    // ---- fused final MLP + projection ----
    finale_kernel<<<dim3((N_ENC + 63) / 64), blk, 0, stream>>>(
        h_enc, WFP, bf1, Wf2, bf2, (float*)d_out, N_ENC);
}

// Round 11
// 369.123 us; speedup vs baseline: 1.7338x; 1.1259x over previous
//
#include <hip/hip_runtime.h>
#include <hip/hip_bf16.h>

#define HDIM 128
#define FIN  32

typedef __hip_bfloat16 bf16t;
using bf16x8 = __attribute__((ext_vector_type(8))) short;
using u16x8  = __attribute__((ext_vector_type(8))) unsigned short;
using f32x4  = __attribute__((ext_vector_type(4))) float;

#define W1P_TOT (5 * 2 * HDIM * HDIM)
#define W2P_TOT (5 * HDIM * HDIM)
#define WEP_TOT (6 * FIN * HDIM)
#define WFP_TOT (HDIM * HDIM)
#define PACK_TOT (W1P_TOT + W2P_TOT + WEP_TOT + WFP_TOT)

__device__ __forceinline__ float reluf(float x) { return x > 0.f ? x : 0.f; }

__device__ __forceinline__ unsigned short f2bf(float f) {
    unsigned int b = __float_as_uint(f);
    b += 0x7FFFu + ((b >> 16) & 1u);       // round-to-nearest-even
    return (unsigned short)(b >> 16);
}
__device__ __forceinline__ float bf2f(unsigned short u) {
    return __uint_as_float(((unsigned int)u) << 16);
}

// ======================= consolidated CSR construction ======================
__global__ __launch_bounds__(256) void hist_all_kernel(
    const int* __restrict__ d0, const int* __restrict__ d1,
    const int* __restrict__ d2, const int* __restrict__ d3,
    const int* __restrict__ d4,
    int c1, int c2, int c3, int c4, int ET,
    int n0, int n1, int n2, int n3, int n4,
    int* __restrict__ deg, int* __restrict__ rank)
{
    int i = blockIdx.x * 256 + threadIdx.x;
    if (i >= ET) return;
    int d, off;
    if      (i < c1) { d = d0[i];      off = n0; }
    else if (i < c2) { d = d1[i - c1]; off = n1; }
    else if (i < c3) { d = d2[i - c2]; off = n2; }
    else if (i < c4) { d = d3[i - c3]; off = n3; }
    else             { d = d4[i - c4]; off = n4; }
    rank[i] = atomicAdd(&deg[off + d], 1);
}

__global__ __launch_bounds__(256) void fill_all_kernel(
    const int* __restrict__ s0, const int* __restrict__ s1,
    const int* __restrict__ s2, const int* __restrict__ s3,
    const int* __restrict__ s4,
    const int* __restrict__ d0, const int* __restrict__ d1,
    const int* __restrict__ d2, const int* __restrict__ d3,
    const int* __restrict__ d4,
    int c1, int c2, int c3, int c4, int ET,
    int n0, int n1, int n2, int n3, int n4,
    const int* __restrict__ start, const int* __restrict__ rank,
    int* __restrict__ eidx)
{
    int i = blockIdx.x * 256 + threadIdx.x;
    if (i >= ET) return;
    int s, d, off;
    if      (i < c1) { s = s0[i];      d = d0[i];      off = n0; }
    else if (i < c2) { s = s1[i - c1]; d = d1[i - c1]; off = n1; }
    else if (i < c3) { s = s2[i - c2]; d = d2[i - c2]; off = n2; }
    else if (i < c4) { s = s3[i - c3]; d = d3[i - c3]; off = n3; }
    else             { s = s4[i - c4]; d = d4[i - c4]; off = n4; }
    eidx[start[off + d] + rank[i]] = s;
}

__global__ __launch_bounds__(256) void scan_blocks_kernel(
    const int* __restrict__ deg, int* __restrict__ start,
    int* __restrict__ bsum, int N)
{
    __shared__ int s[256];
    const int t = threadIdx.x;
    const int base = blockIdx.x * 1024;
    int v[4], tsum = 0;
    #pragma unroll
    for (int i = 0; i < 4; ++i) {
        int idx = base + t * 4 + i;
        v[i] = (idx < N) ? deg[idx] : 0;
        tsum += v[i];
    }
    s[t] = tsum; __syncthreads();
    for (int off = 1; off < 256; off <<= 1) {
        int x = (t >= off) ? s[t - off] : 0;
        __syncthreads();
        s[t] += x;
        __syncthreads();
    }
    if (t == 255) bsum[blockIdx.x] = s[255];
    int run = s[t] - tsum;
    #pragma unroll
    for (int i = 0; i < 4; ++i) {
        int idx = base + t * 4 + i;
        if (idx < N) start[idx] = run;
        run += v[i];
    }
}

__global__ __launch_bounds__(256) void scan_top_kernel(int* __restrict__ bsum, int B)
{
    __shared__ int s[256];
    const int t = threadIdx.x;
    int v[4], tsum = 0;
    #pragma unroll
    for (int i = 0; i < 4; ++i) {
        int idx = t * 4 + i;
        v[i] = (idx < B) ? bsum[idx] : 0;
        tsum += v[i];
    }
    s[t] = tsum; __syncthreads();
    for (int off = 1; off < 256; off <<= 1) {
        int x = (t >= off) ? s[t - off] : 0;
        __syncthreads();
        s[t] += x;
        __syncthreads();
    }
    int run = s[t] - tsum;
    #pragma unroll
    for (int i = 0; i < 4; ++i) {
        int idx = t * 4 + i;
        if (idx < B) bsum[idx] = run;
        run += v[i];
    }
}

__global__ __launch_bounds__(256) void scan_add_kernel(
    int* __restrict__ start, const int* __restrict__ bsum, int N)
{
    int i = blockIdx.x * 256 + threadIdx.x;
    if (i < N) start[i] += bsum[i >> 10];
}

// ======================= gather (16 lanes/row, 16B loads) ===================
__global__ __launch_bounds__(256) void gather_kernel(
    const bf16t* __restrict__ h, const int* __restrict__ eidx,
    const int* __restrict__ start, const int* __restrict__ deg,
    bf16t* __restrict__ msg, int N)
{
    int r = blockIdx.x * 16 + (threadIdx.x >> 4);
    if (r >= N) return;
    int lane = threadIdx.x & 15;
    int s0 = start[r], cnt = deg[r];
    float acc[8] = {0.f, 0.f, 0.f, 0.f, 0.f, 0.f, 0.f, 0.f};
    for (int j = s0; j < s0 + cnt; ++j) {
        int s = eidx[j];
        u16x8 v = *(const u16x8*)&h[(size_t)s * HDIM + lane * 8];
        #pragma unroll
        for (int k = 0; k < 8; ++k) acc[k] += bf2f(v[k]);
    }
    u16x8 o;
    #pragma unroll
    for (int k = 0; k < 8; ++k) o[k] = f2bf(acc[k]);
    *(u16x8*)&msg[(size_t)r * HDIM + lane * 8] = o;
}

// ======================= merged weight repack ===============================
__global__ __launch_bounds__(256) void pack_all_kernel(
    const float* __restrict__ W1t, const float* __restrict__ W2t,
    const float* __restrict__ We,  const float* __restrict__ Wf1,
    bf16t* __restrict__ W1P, bf16t* __restrict__ W2P,
    bf16t* __restrict__ WeP, bf16t* __restrict__ WfP)
{
    int q = blockIdx.x * 256 + threadIdx.x;
    if (q < W1P_TOT) {
        int L = q >> 15, r = q & 32767;
        int j = r & 7, l = (r >> 3) & 63, mt = (r >> 9) & 7, kc = (r >> 12) & 7;
        float v = W1t[(size_t)L * 2 * HDIM * HDIM +
                      (size_t)(kc * 32 + ((l >> 4) & 3) * 8 + j) * HDIM + mt * 16 + (l & 15)];
        *(unsigned short*)&W1P[q] = f2bf(v);
        return;
    }
    q -= W1P_TOT;
    if (q < W2P_TOT) {
        int L = q >> 14, r = q & 16383;
        int j = r & 7, l = (r >> 3) & 63, mt = (r >> 9) & 7, kc = (r >> 12) & 3;
        float v = W2t[(size_t)L * HDIM * HDIM +
                      (size_t)(kc * 32 + ((l >> 4) & 3) * 8 + j) * HDIM + mt * 16 + (l & 15)];
        *(unsigned short*)&W2P[q] = f2bf(v);
        return;
    }
    q -= W2P_TOT;
    if (q < WEP_TOT) {
        int enc = q >> 12, r = q & 4095;
        int j = r & 7, l = (r >> 3) & 63, mt = (r >> 9) & 7;
        int k = ((l >> 4) & 3) * 8 + j;
        float v = We[(size_t)enc * FIN * HDIM + (size_t)k * HDIM + mt * 16 + (l & 15)];
        *(unsigned short*)&WeP[q] = f2bf(v);
        return;
    }
    q -= WEP_TOT;
    if (q < WFP_TOT) {
        int r = q;
        int j = r & 7, l = (r >> 3) & 63, mt = (r >> 9) & 7, kc = (r >> 12) & 3;
        float v = Wf1[(size_t)(kc * 32 + ((l >> 4) & 3) * 8 + j) * HDIM + mt * 16 + (l & 15)];
        *(unsigned short*)&WfP[q] = f2bf(v);
    }
}

// ======================= MFMA encoder (h_col only) ==========================
__global__ __launch_bounds__(256) void enc_mfma_kernel(
    const float* __restrict__ x, const bf16t* __restrict__ WP,
    const float* __restrict__ b, bf16t* __restrict__ h, int N)
{
    __shared__ bf16t x_s[64 * 36];
    const int tid  = threadIdx.x;
    const int row0 = blockIdx.x * 64;
    const int wave = tid >> 6, lane = tid & 63;
    const int l15 = lane & 15, l16 = lane >> 4;

    #pragma unroll
    for (int i = 0; i < 2; ++i) {
        int f = tid + i * 256;
        int r = f >> 3, c4 = f & 7;
        int row = row0 + r; if (row >= N) row = N - 1;
        float4 v = *(const float4*)&x[(size_t)row * FIN + c4 * 4];
        ushort4 u;
        u.x = f2bf(v.x); u.y = f2bf(v.y); u.z = f2bf(v.z); u.w = f2bf(v.w);
        *(ushort4*)&x_s[r * 36 + c4 * 4] = u;
    }
    __syncthreads();

    f32x4 acc[2][4];
    #pragma unroll
    for (int m = 0; m < 2; ++m)
        #pragma unroll
        for (int n = 0; n < 4; ++n)
            #pragma unroll
            for (int i = 0; i < 4; ++i) acc[m][n][i] = 0.f;

    bf16x8 a[2], bb[4];
    #pragma unroll
    for (int m = 0; m < 2; ++m)
        a[m] = *(const bf16x8*)&WP[(((wave * 2 + m)) * 64 + lane) * 8];
    #pragma unroll
    for (int n = 0; n < 4; ++n)
        bb[n] = *(const bf16x8*)&x_s[(n * 16 + l15) * 36 + l16 * 8];
    #pragma unroll
    for (int m = 0; m < 2; ++m)
        #pragma unroll
        for (int n = 0; n < 4; ++n)
            acc[m][n] = __builtin_amdgcn_mfma_f32_16x16x32_bf16(a[m], bb[n], acc[m][n], 0, 0, 0);

    #pragma unroll
    for (int m = 0; m < 2; ++m) {
        int mt = wave * 2 + m;
        float4 bv = *(const float4*)&b[mt * 16 + l16 * 4];
        #pragma unroll
        for (int n = 0; n < 4; ++n) {
            int row = row0 + n * 16 + l15;
            if (row < N) {
                ushort4 u;
                u.x = f2bf(reluf(acc[m][n][0] + bv.x));
                u.y = f2bf(reluf(acc[m][n][1] + bv.y));
                u.z = f2bf(reluf(acc[m][n][2] + bv.z));
                u.w = f2bf(reluf(acc[m][n][3] + bv.w));
                *(ushort4*)&h[(size_t)row * HDIM + mt * 16 + l16 * 4] = u;
            }
        }
    }
}

// ======================= fused enc + combine (+ optional finale) ============
#define ACT_STRIDE 264   // 256 + 8 bf16 pad
template<int FINAL>
__global__ __launch_bounds__(256) void fused_enc_combine_kernel(
    const float* __restrict__ x, const bf16t* __restrict__ WEPl,
    const float* __restrict__ be, const bf16t* __restrict__ msg,
    const bf16t* __restrict__ W1P, const float* __restrict__ b1,
    const bf16t* __restrict__ W2P, const float* __restrict__ b2,
    bf16t* __restrict__ hout, int N,
    const bf16t* __restrict__ WfP, const float* __restrict__ fb1,
    const float* __restrict__ fw2, const float* __restrict__ fb2,
    float* __restrict__ out)
{
    __shared__ bf16t x_s[64 * 36];             //  4,608 B
    __shared__ bf16t act_s[64 * ACT_STRIDE];   // 33,792 B
    __shared__ float o_s[64];

    const int tid  = threadIdx.x;
    const int row0 = blockIdx.x * 64;
    const int wave = tid >> 6, lane = tid & 63;
    const int l15 = lane & 15, l16 = lane >> 4;

    if (FINAL && tid < 64) o_s[tid] = 0.f;

    #pragma unroll
    for (int i = 0; i < 2; ++i) {
        int f = tid + i * 256;
        int r = f >> 3, c4 = f & 7;
        int row = row0 + r; if (row >= N) row = N - 1;
        float4 v = *(const float4*)&x[(size_t)row * FIN + c4 * 4];
        ushort4 u;
        u.x = f2bf(v.x); u.y = f2bf(v.y); u.z = f2bf(v.z); u.w = f2bf(v.w);
        *(ushort4*)&x_s[r * 36 + c4 * 4] = u;
    }
    #pragma unroll
    for (int i = 0; i < 4; ++i) {
        int f = tid + i * 256;
        int r = f >> 4, seg = f & 15;
        int row = row0 + r; if (row >= N) row = N - 1;
        *(float4*)&act_s[r * ACT_STRIDE + 128 + seg * 8] =
            *(const float4*)&msg[(size_t)row * HDIM + seg * 8];
    }
    __syncthreads();

    // inline encoder: relu(x@We+be) -> act[:,0:128]
    {
        f32x4 eacc[2][4];
        #pragma unroll
        for (int m = 0; m < 2; ++m)
            #pragma unroll
            for (int n = 0; n < 4; ++n)
                #pragma unroll
                for (int i = 0; i < 4; ++i) eacc[m][n][i] = 0.f;

        bf16x8 a[2], bb[4];
        #pragma unroll
        for (int m = 0; m < 2; ++m)
            a[m] = *(const bf16x8*)&WEPl[(((wave * 2 + m)) * 64 + lane) * 8];
        #pragma unroll
        for (int n = 0; n < 4; ++n)
            bb[n] = *(const bf16x8*)&x_s[(n * 16 + l15) * 36 + l16 * 8];
        #pragma unroll
        for (int m = 0; m < 2; ++m)
            #pragma unroll
            for (int n = 0; n < 4; ++n)
                eacc[m][n] = __builtin_amdgcn_mfma_f32_16x16x32_bf16(a[m], bb[n], eacc[m][n], 0, 0, 0);

        #pragma unroll
        for (int m = 0; m < 2; ++m) {
            int mt = wave * 2 + m;
            float4 bv = *(const float4*)&be[mt * 16 + l16 * 4];
            #pragma unroll
            for (int n = 0; n < 4; ++n) {
                int rl = n * 16 + l15;
                ushort4 u;
                u.x = f2bf(reluf(eacc[m][n][0] + bv.x));
                u.y = f2bf(reluf(eacc[m][n][1] + bv.y));
                u.z = f2bf(reluf(eacc[m][n][2] + bv.z));
                u.w = f2bf(reluf(eacc[m][n][3] + bv.w));
                *(ushort4*)&act_s[rl * ACT_STRIDE + mt * 16 + l16 * 4] = u;
            }
        }
    }
    __syncthreads();

    // GEMM1: K=256
    f32x4 acc1[2][4];
    #pragma unroll
    for (int m = 0; m < 2; ++m)
        #pragma unroll
        for (int n = 0; n < 4; ++n)
            #pragma unroll
            for (int i = 0; i < 4; ++i) acc1[m][n][i] = 0.f;

    for (int kc = 0; kc < 8; ++kc) {
        bf16x8 a[2], b[4];
        #pragma unroll
        for (int m = 0; m < 2; ++m) {
            int mt = wave * 2 + m;
            a[m] = *(const bf16x8*)&W1P[((kc * 8 + mt) * 64 + lane) * 8];
        }
        #pragma unroll
        for (int n = 0; n < 4; ++n)
            b[n] = *(const bf16x8*)&act_s[(n * 16 + l15) * ACT_STRIDE + kc * 32 + l16 * 8];
        #pragma unroll
        for (int m = 0; m < 2; ++m)
            #pragma unroll
            for (int n = 0; n < 4; ++n)
                acc1[m][n] = __builtin_amdgcn_mfma_f32_16x16x32_bf16(a[m], b[n], acc1[m][n], 0, 0, 0);
    }
    __syncthreads();

    // z1 = relu(acc1 + b1) -> act[:,0:128] (aliased)
    #pragma unroll
    for (int m = 0; m < 2; ++m) {
        int mt = wave * 2 + m;
        float4 bb = *(const float4*)&b1[mt * 16 + l16 * 4];
        #pragma unroll
        for (int n = 0; n < 4; ++n) {
            int zrow = n * 16 + l15;
            ushort4 u;
            u.x = f2bf(reluf(acc1[m][n][0] + bb.x));
            u.y = f2bf(reluf(acc1[m][n][1] + bb.y));
            u.z = f2bf(reluf(acc1[m][n][2] + bb.z));
            u.w = f2bf(reluf(acc1[m][n][3] + bb.w));
            *(ushort4*)&act_s[zrow * ACT_STRIDE + mt * 16 + l16 * 4] = u;
        }
    }
    __syncthreads();

    // GEMM2: K=128
    f32x4 acc2[2][4];
    #pragma unroll
    for (int m = 0; m < 2; ++m)
        #pragma unroll
        for (int n = 0; n < 4; ++n)
            #pragma unroll
            for (int i = 0; i < 4; ++i) acc2[m][n][i] = 0.f;

    for (int kc = 0; kc < 4; ++kc) {
        bf16x8 a[2], b[4];
        #pragma unroll
        for (int m = 0; m < 2; ++m) {
            int mt = wave * 2 + m;
            a[m] = *(const bf16x8*)&W2P[((kc * 8 + mt) * 64 + lane) * 8];
        }
        #pragma unroll
        for (int n = 0; n < 4; ++n)
            b[n] = *(const bf16x8*)&act_s[(n * 16 + l15) * ACT_STRIDE + kc * 32 + l16 * 8];
        #pragma unroll
        for (int m = 0; m < 2; ++m)
            #pragma unroll
            for (int n = 0; n < 4; ++n)
                acc2[m][n] = __builtin_amdgcn_mfma_f32_16x16x32_bf16(a[m], b[n], acc2[m][n], 0, 0, 0);
    }

    if (!FINAL) {
        #pragma unroll
        for (int m = 0; m < 2; ++m) {
            int mt = wave * 2 + m;
            float4 bb = *(const float4*)&b2[mt * 16 + l16 * 4];
            #pragma unroll
            for (int n = 0; n < 4; ++n) {
                int row = row0 + n * 16 + l15;
                if (row < N) {
                    ushort4 u;
                    u.x = f2bf(reluf(acc2[m][n][0] + bb.x));
                    u.y = f2bf(reluf(acc2[m][n][1] + bb.y));
                    u.z = f2bf(reluf(acc2[m][n][2] + bb.z));
                    u.w = f2bf(reluf(acc2[m][n][3] + bb.w));
                    *(ushort4*)&hout[(size_t)row * HDIM + mt * 16 + l16 * 4] = u;
                }
            }
        }
    } else {
        // h_enc tile -> act[:,0:128] (z dead; skip the global round trip)
        __syncthreads();   // all GEMM2 reads of z complete
        #pragma unroll
        for (int m = 0; m < 2; ++m) {
            int mt = wave * 2 + m;
            float4 bb = *(const float4*)&b2[mt * 16 + l16 * 4];
            #pragma unroll
            for (int n = 0; n < 4; ++n) {
                int rl = n * 16 + l15;
                ushort4 u;
                u.x = f2bf(reluf(acc2[m][n][0] + bb.x));
                u.y = f2bf(reluf(acc2[m][n][1] + bb.y));
                u.z = f2bf(reluf(acc2[m][n][2] + bb.z));
                u.w = f2bf(reluf(acc2[m][n][3] + bb.w));
                *(ushort4*)&act_s[rl * ACT_STRIDE + mt * 16 + l16 * 4] = u;
            }
        }
        __syncthreads();

        // finale GEMM: t1 = relu(h @ Wf1 + fb1), out = t1 . fw2 + fb2
        f32x4 acc3[2][4];
        #pragma unroll
        for (int m = 0; m < 2; ++m)
            #pragma unroll
            for (int n = 0; n < 4; ++n)
                #pragma unroll
                for (int i = 0; i < 4; ++i) acc3[m][n][i] = 0.f;

        for (int kc = 0; kc < 4; ++kc) {
            bf16x8 a[2], b[4];
            #pragma unroll
            for (int m = 0; m < 2; ++m) {
                int mt = wave * 2 + m;
                a[m] = *(const bf16x8*)&WfP[((kc * 8 + mt) * 64 + lane) * 8];
            }
            #pragma unroll
            for (int n = 0; n < 4; ++n)
                b[n] = *(const bf16x8*)&act_s[(n * 16 + l15) * ACT_STRIDE + kc * 32 + l16 * 8];
            #pragma unroll
            for (int m = 0; m < 2; ++m)
                #pragma unroll
                for (int n = 0; n < 4; ++n)
                    acc3[m][n] = __builtin_amdgcn_mfma_f32_16x16x32_bf16(a[m], b[n], acc3[m][n], 0, 0, 0);
        }

        float s[4] = {0.f, 0.f, 0.f, 0.f};
        #pragma unroll
        for (int m = 0; m < 2; ++m) {
            int mt = wave * 2 + m;
            float4 bb = *(const float4*)&fb1[mt * 16 + l16 * 4];
            float4 ww = *(const float4*)&fw2[mt * 16 + l16 * 4];
            #pragma unroll
            for (int n = 0; n < 4; ++n) {
                s[n] += reluf(acc3[m][n][0] + bb.x) * ww.x
                      + reluf(acc3[m][n][1] + bb.y) * ww.y
                      + reluf(acc3[m][n][2] + bb.z) * ww.z
                      + reluf(acc3[m][n][3] + bb.w) * ww.w;
            }
        }
        #pragma unroll
        for (int n = 0; n < 4; ++n) {
            s[n] += __shfl_xor(s[n], 16, 64);
            s[n] += __shfl_xor(s[n], 32, 64);
            if (l16 == 0) atomicAdd(&o_s[n * 16 + l15], s[n]);
        }
        __syncthreads();
        if (tid < 64) {
            int row = row0 + tid;
            if (row < N) out[row] = o_s[tid] + fb2[0];
        }
    }
}

__global__ __launch_bounds__(256) void sentinel_kernel(float* out, int n, float val)
{
    int i = blockIdx.x * 256 + threadIdx.x;
    if (i < n) out[i] = (i == 0) ? val : 0.f;
}

extern "C" void kernel_launch(void* const* d_in, const int* in_sizes, int n_in,
                              void* d_out, int out_size, void* d_ws, size_t ws_size,
                              hipStream_t stream)
{
    const float* x_col  = (const float*)d_in[0];
    const float* x_filt = (const float*)d_in[1];
    const float* x_pred = (const float*)d_in[2];
    const float* x_scan = (const float*)d_in[3];
    const float* x_join = (const float*)d_in[4];
    const float* x_enc  = (const float*)d_in[5];
    const float* W_enc  = (const float*)d_in[6];
    const float* b_enc  = (const float*)d_in[7];
    const float* W1t    = (const float*)d_in[8];
    const float* b1t    = (const float*)d_in[9];
    const float* W2t    = (const float*)d_in[10];
    const float* b2t    = (const float*)d_in[11];
    const float* Wf1    = (const float*)d_in[12];
    const float* bf1    = (const float*)d_in[13];
    const float* Wf2    = (const float*)d_in[14];
    const float* bf2    = (const float*)d_in[15];
    const int* src_cf = (const int*)d_in[16];
    const int* dst_cf = (const int*)d_in[17];
    const int* src_fp = (const int*)d_in[18];
    const int* dst_fp = (const int*)d_in[19];
    const int* src_ps = (const int*)d_in[20];
    const int* dst_ps = (const int*)d_in[21];
    const int* src_sj = (const int*)d_in[22];
    const int* dst_sj = (const int*)d_in[23];
    const int* src_je = (const int*)d_in[24];
    const int* dst_je = (const int*)d_in[25];

    const int N_COL  = in_sizes[0] / FIN;
    const int N_FILT = in_sizes[1] / FIN;
    const int N_PRED = in_sizes[2] / FIN;
    const int N_SCAN = in_sizes[3] / FIN;
    const int N_JOIN = in_sizes[4] / FIN;
    const int N_ENC  = in_sizes[5] / FIN;
    const int E_CF = in_sizes[16];
    const int E_FP = in_sizes[18];
    const int E_PS = in_sizes[20];
    const int E_SJ = in_sizes[22];
    const int E_JE = in_sizes[24];

    // concatenated node / edge spaces
    const int n0 = 0;
    const int n1 = n0 + N_FILT;
    const int n2 = n1 + N_PRED;
    const int n3 = n2 + N_SCAN;
    const int n4 = n3 + N_JOIN;
    const int NT = n4 + N_ENC;
    const int c1 = E_CF;
    const int c2 = c1 + E_FP;
    const int c3 = c2 + E_PS;
    const int c4 = c3 + E_SJ;
    const int ET = c4 + E_JE;

    // ---- workspace layout ----
    size_t Mf = 0;
    {
        size_t c;
        c = (size_t)N_FILT * HDIM; if (c > Mf) Mf = c;
        c = (size_t)N_PRED * HDIM; if (c > Mf) Mf = c;
        c = (size_t)N_SCAN * HDIM; if (c > Mf) Mf = c;
        c = (size_t)N_JOIN * HDIM; if (c > Mf) Mf = c;
        c = (size_t)N_ENC  * HDIM; if (c > Mf) Mf = c;
    }
    size_t Hf = (size_t)N_COL * HDIM;
    { size_t c = (size_t)(N_FILT + N_PRED) * HDIM; if (c > Hf) Hf = c; }
    { size_t c = (size_t)(N_SCAN + N_JOIN + N_ENC + N_PRED) * HDIM; if (c > Hf) Hf = c; }

    size_t msgB  = ((Mf * 2) + 255) & ~(size_t)255;
    size_t hB    = ((Hf * 2) + 255) & ~(size_t)255;
    size_t intB  = (((size_t)NT * 4) + 255) & ~(size_t)255;
    size_t eidxB = (((size_t)ET * 4) + 255) & ~(size_t)255;
    size_t wpB   = (((size_t)PACK_TOT * 2) + 255) & ~(size_t)255;
    size_t need  = msgB + hB + 2 * intB + 2 * eidxB + wpB + 8192;

    if (!d_ws || ws_size < need) {
        float val = 1.0e6f + (float)(ws_size >> 20);
        sentinel_kernel<<<dim3((out_size + 255) / 256), dim3(256), 0, stream>>>(
            (float*)d_out, out_size, val);
        return;
    }

    char* base = (char*)d_ws;
    bf16t* msg  = (bf16t*)base;                       base += msgB;
    bf16t* H    = (bf16t*)base;                       base += hB;
    int* deg    = (int*)base;                         base += intB;
    int* start  = (int*)base;                         base += intB;
    int* rank   = (int*)base;                         base += eidxB;
    int* eidx   = (int*)base;                         base += eidxB;
    bf16t* W1P  = (bf16t*)base;                       base += (size_t)W1P_TOT * 2;
    bf16t* W2P  = (bf16t*)base;                       base += (size_t)W2P_TOT * 2;
    bf16t* WEP  = (bf16t*)base;                       base += (size_t)WEP_TOT * 2;
    bf16t* WFP  = (bf16t*)base;                       base += (size_t)WFP_TOT * 2;
    int* bsum   = (int*)(((size_t)base + 255) & ~(size_t)255);

    bf16t* h_col  = H;                                 // dead after gather0
    bf16t* h_filt = H;                                 // overwritten by fused L0
    bf16t* h_pred = H + (size_t)N_FILT * HDIM;
    bf16t* h_scan = H;                                 // h_filt dead by then
    bf16t* h_join = H + (size_t)N_SCAN * HDIM;

    const dim3 blk(256);

    // ---- consolidated CSR build (atomic-free fill) ----
    hipMemsetAsync(deg, 0, (size_t)NT * sizeof(int), stream);
    hist_all_kernel<<<dim3((ET + 255) / 256), blk, 0, stream>>>(
        dst_cf, dst_fp, dst_ps, dst_sj, dst_je,
        c1, c2, c3, c4, ET, n0, n1, n2, n3, n4, deg, rank);
    int B = (NT + 1023) / 1024;
    scan_blocks_kernel<<<dim3(B), blk, 0, stream>>>(deg, start, bsum, NT);
    scan_top_kernel<<<dim3(1), blk, 0, stream>>>(bsum, B);
    scan_add_kernel<<<dim3((NT + 255) / 256), blk, 0, stream>>>(start, bsum, NT);
    fill_all_kernel<<<dim3((ET + 255) / 256), blk, 0, stream>>>(
        src_cf, src_fp, src_ps, src_sj, src_je,
        dst_cf, dst_fp, dst_ps, dst_sj, dst_je,
        c1, c2, c3, c4, ET, n0, n1, n2, n3, n4, start, rank, eidx);

    // ---- merged weight repack ----
    pack_all_kernel<<<dim3((PACK_TOT + 255) / 256), blk, 0, stream>>>(
        W1t, W2t, W_enc, Wf1, W1P, W2P, WEP, WFP);

    // ---- h_col encoder ----
    enc_mfma_kernel<<<dim3((N_COL + 63) / 64), blk, 0, stream>>>(
        x_col, WEP, b_enc, h_col, N_COL);

    // ---- level 0: column -> filter ----
    gather_kernel<<<dim3((N_FILT + 15) / 16), blk, 0, stream>>>(
        h_col, eidx, start + n0, deg + n0, msg, N_FILT);
    fused_enc_combine_kernel<0><<<dim3((N_FILT + 63) / 64), blk, 0, stream>>>(
        x_filt, WEP + 1 * FIN * HDIM, b_enc + 1 * HDIM, msg,
        W1P, b1t, W2P, b2t, h_filt, N_FILT,
        nullptr, nullptr, nullptr, nullptr, nullptr);

    // ---- level 1: filter -> pred ----
    gather_kernel<<<dim3((N_PRED + 15) / 16), blk, 0, stream>>>(
        h_filt, eidx, start + n1, deg + n1, msg, N_PRED);
    fused_enc_combine_kernel<0><<<dim3((N_PRED + 63) / 64), blk, 0, stream>>>(
        x_pred, WEP + 2 * FIN * HDIM, b_enc + 2 * HDIM, msg,
        W1P + 1 * 2 * HDIM * HDIM, b1t + 1 * HDIM,
        W2P + 1 * HDIM * HDIM, b2t + 1 * HDIM, h_pred, N_PRED,
        nullptr, nullptr, nullptr, nullptr, nullptr);

    // ---- level 2: pred -> scan ----
    gather_kernel<<<dim3((N_SCAN + 15) / 16), blk, 0, stream>>>(
        h_pred, eidx, start + n2, deg + n2, msg, N_SCAN);
    fused_enc_combine_kernel<0><<<dim3((N_SCAN + 63) / 64), blk, 0, stream>>>(
        x_scan, WEP + 3 * FIN * HDIM, b_enc + 3 * HDIM, msg,
        W1P + 2 * 2 * HDIM * HDIM, b1t + 2 * HDIM,
        W2P + 2 * HDIM * HDIM, b2t + 2 * HDIM, h_scan, N_SCAN,
        nullptr, nullptr, nullptr, nullptr, nullptr);

    // ---- level 3: scan -> join ----
    gather_kernel<<<dim3((N_JOIN + 15) / 16), blk, 0, stream>>>(
        h_scan, eidx, start + n3, deg + n3, msg, N_JOIN);
    fused_enc_combine_kernel<0><<<dim3((N_JOIN + 63) / 64), blk, 0, stream>>>(
        x_join, WEP + 4 * FIN * HDIM, b_enc + 4 * HDIM, msg,
        W1P + 3 * 2 * HDIM * HDIM, b1t + 3 * HDIM,
        W2P + 3 * HDIM * HDIM, b2t + 3 * HDIM, h_join, N_JOIN,
        nullptr, nullptr, nullptr, nullptr, nullptr);

    // ---- level 4: join -> encode, finale fused in (writes d_out directly) ----
    gather_kernel<<<dim3((N_ENC + 15) / 16), blk, 0, stream>>>(
        h_join, eidx, start + n4, deg + n4, msg, N_ENC);
    fused_enc_combine_kernel<1><<<dim3((N_ENC + 63) / 64), blk, 0, stream>>>(
        x_enc, WEP + 5 * FIN * HDIM, b_enc + 5 * HDIM, msg,
        W1P + 4 * 2 * HDIM * HDIM, b1t + 4 * HDIM,
        W2P + 4 * HDIM * HDIM, b2t + 4 * HDIM, nullptr, N_ENC,
        WFP, bf1, Wf2, bf2, (float*)d_out);
}